// Round 8
// baseline (800.759 us; speedup 1.0000x reference)
//
#include <hip/hip_runtime.h>
#include <hip/hip_bf16.h>
#include <math.h>

#define S 4096
#define HQ 8
#define NKVH 4
#define D 256
#define HID 2304
#define SW 2048
#define QDIM 2048
#define KVDIM 1024
#define QKVDIM 4096          // fused Q(2048) | K(1024) | V(1024)
#define SCALE 0.0625f
#define SOFTCAP 50.0f

typedef __attribute__((ext_vector_type(4))) float f32x4;
typedef __attribute__((ext_vector_type(8))) short short8;   // 8 bf16 = 4 VGPRs (MFMA A/B frag)

__device__ __forceinline__ float bf2f(unsigned v) { return __uint_as_float(v << 16); }
__device__ __forceinline__ unsigned f2bf(float f) {
    unsigned u = __float_as_uint(f);
    return (u + 0x7fffu + ((u >> 16) & 1u)) >> 16;   // round-to-nearest-even
}

__device__ __forceinline__ void store_c(float* p, float v) { *p = v; }
__device__ __forceinline__ void store_c(unsigned short* p, float v) { *p = (unsigned short)f2bf(v); }

// async global->LDS, 16B per lane; lds dst is wave-uniform base (HW adds lane*16)
__device__ __forceinline__ void glls16(const void* g, void* l) {
    __builtin_amdgcn_global_load_lds(
        (const __attribute__((address_space(1))) unsigned int*)g,
        (__attribute__((address_space(3))) unsigned int*)l, 16, 0, 0);
}

// ---------------------------------------------------------------------------
// fp32 -> bf16 elementwise (float4 per thread)
// ---------------------------------------------------------------------------
__global__ __launch_bounds__(256) void cvt_bf16(const float* __restrict__ in,
                                                unsigned short* __restrict__ out)
{
    int i = blockIdx.x * 256 + threadIdx.x;
    float4 v = ((const float4*)in)[i];
    uint2 o;
    o.x = f2bf(v.x) | (f2bf(v.y) << 16);
    o.y = f2bf(v.z) | (f2bf(v.w) << 16);
    ((uint2*)out)[i] = o;
}

// ---------------------------------------------------------------------------
// 128x128-tile GEMM (verified m97-style structure) — kept for O-projection.
// C[M][N] = A[M][K] @ B[N][K]^T, bf16 in, fp32 accumulate, TC out.
// ---------------------------------------------------------------------------
template <typename TC>
__global__ __launch_bounds__(256) void bf16_gemm_bt(const unsigned short* __restrict__ A,
                                                    const unsigned short* __restrict__ B,
                                                    TC* __restrict__ C,
                                                    int M, int N, int K)
{
    __shared__ unsigned short As[2][16 * 512];   // 16 frags x 1 KiB per buffer
    __shared__ unsigned short Bs[2][16 * 512];
    const int t = threadIdx.x;

    // bijective XCD swizzle of the flattened tile id
    const int nbx = gridDim.x;
    const int nwg = nbx * gridDim.y;
    int flat = blockIdx.y * nbx + blockIdx.x;
    const int q8 = nwg >> 3, r8 = nwg & 7;
    const int xcd = flat & 7, orig = flat >> 3;
    const int wg = (xcd < r8 ? xcd * (q8 + 1) : r8 * (q8 + 1) + (xcd - r8) * q8) + orig;
    // grouped raster: bands of 8 m-tiles, n sweeps within a band
    const int band = wg / (8 * nbx);
    const int rem  = wg - band * 8 * nbx;
    const int m0 = (band * 8 + (rem & 7)) * 128;
    const int n0 = (rem >> 3) * 128;

    const int w = t >> 6, lid = t & 63, n16 = lid & 15, quad = lid >> 4;
    const int wm = (w >> 1) * 64, wn = (w & 1) * 64;

    f32x4 acc[4][4] = {};

    auto stage = [&](int buf, int k0) {
        #pragma unroll
        for (int it = 0; it < 4; ++it) {
            int f  = it * 4 + w;              // wave-uniform frag id 0..15
            int fm = f >> 1, fk = f & 1;
            const size_t goff = (size_t)(fm * 16 + n16) * K + k0 + fk * 32 + quad * 8;
            glls16(A + (size_t)m0 * K + goff, &As[buf][f * 512]);
            glls16(B + (size_t)n0 * K + goff, &Bs[buf][f * 512]);
        }
    };

    const int nk = K / 64;
    stage(0, 0);
    int cur = 0;
    for (int kk = 0; kk < nk; ++kk) {
        asm volatile("s_waitcnt vmcnt(0)" ::: "memory");   // own staging done
        __syncthreads();                                   // everyone's visible
        if (kk + 1 < nk) stage(cur ^ 1, (kk + 1) * 64);    // prefetch next panel
        #pragma unroll
        for (int ks = 0; ks < 2; ++ks) {
            short8 af[4], bfr[4];
            #pragma unroll
            for (int x = 0; x < 4; ++x) {
                af[x]  = *(const short8*)(&As[cur][(((wm >> 4) + x) * 2 + ks) * 512 + lid * 8]);
                bfr[x] = *(const short8*)(&Bs[cur][(((wn >> 4) + x) * 2 + ks) * 512 + lid * 8]);
            }
            __builtin_amdgcn_s_setprio(1);
            #pragma unroll
            for (int i = 0; i < 4; ++i)
                #pragma unroll
                for (int j = 0; j < 4; ++j)
                    acc[i][j] = __builtin_amdgcn_mfma_f32_16x16x32_bf16(af[i], bfr[j], acc[i][j], 0, 0, 0);
            __builtin_amdgcn_s_setprio(0);
        }
        cur ^= 1;
    }

    #pragma unroll
    for (int i = 0; i < 4; ++i) {
        #pragma unroll
        for (int j = 0; j < 4; ++j) {
            int rbase = m0 + wm + i * 16 + quad * 4;
            int col   = n0 + wn + j * 16 + n16;
            #pragma unroll
            for (int rg = 0; rg < 4; ++rg)
                store_c(C + (size_t)(rbase + rg) * N + col, acc[i][j][rg]);
        }
    }
}

// ---------------------------------------------------------------------------
// 256x256-tile 8-phase GEMM (T3+T4: counted vmcnt), bf16->bf16. 512 threads =
// 8 waves (2m x 4n), per-wave output 128x64, BK=64, 2 K-tiles/iteration.
// Fragment-major LDS => conflict-free without byte-swizzle. LDS = 128 KiB.
// Staging schedule + per-phase vmcnt ledger as verified in R6 (passing).
// ---------------------------------------------------------------------------
__global__ __launch_bounds__(512, 2) void bf16_gemm_8ph(const unsigned short* __restrict__ A,
                                                        const unsigned short* __restrict__ B,
                                                        unsigned short* __restrict__ C,
                                                        int M, int N, int K)
{
    __shared__ unsigned short As[2][32 * 512];   // 32 frags (16 m x 2 ks) x 1 KiB
    __shared__ unsigned short Bs[2][32 * 512];   // 32 frags (16 n x 2 ks) x 1 KiB
    const int t = threadIdx.x;
    const int w = t >> 6, lid = t & 63, n16 = lid & 15, quad = lid >> 4;

    // XCD chunk swizzle (grid = 256, 32 blocks/XCD contiguous)
    const int flat = blockIdx.x;
    const int wg = (flat & 7) * 32 + (flat >> 3);
    const int m0 = (wg >> 4) * 256, n0 = (wg & 15) * 256;

    const int wmf = (w >> 2) * 8;             // wave m-frag base (0 or 8)
    const int wnf = (w & 3) * 4;              // wave n-frag base (0,4,8,12)
    const int fnw = (w >> 1) * 4 + (w & 1);   // B nh0 staging frag for this wave

    f32x4 acc[8][4] = {};

    auto stageA = [&](int buf, int k0, int fm) {
        glls16(A + (size_t)(m0 + fm * 16 + n16) * K + k0 + quad * 8,
               &As[buf][(fm * 2 + 0) * 512]);
        glls16(A + (size_t)(m0 + fm * 16 + n16) * K + k0 + 32 + quad * 8,
               &As[buf][(fm * 2 + 1) * 512]);
    };
    auto stageB = [&](int buf, int k0, int fn) {
        glls16(B + (size_t)(n0 + fn * 16 + n16) * K + k0 + quad * 8,
               &Bs[buf][(fn * 2 + 0) * 512]);
        glls16(B + (size_t)(n0 + fn * 16 + n16) * K + k0 + 32 + quad * 8,
               &Bs[buf][(fn * 2 + 1) * 512]);
    };
    // bijective wave->frag assignments matching the read sets:
    auto sAm0 = [&](int buf, int k0){ stageA(buf, k0, (w & 3) + (w >> 2) * 8); };      // {0..3, 8..11}
    auto sAm1 = [&](int buf, int k0){ stageA(buf, k0, 4 + (w & 3) + (w >> 2) * 8); };  // {4..7, 12..15}
    auto sBn0 = [&](int buf, int k0){ stageB(buf, k0, fnw); };                          // {0,1,4,5,8,9,12,13}
    auto sBn1 = [&](int buf, int k0){ stageB(buf, k0, fnw + 2); };                      // {2,3,6,7,10,11,14,15}

#define GPHASE(mh, nh, buf, STAGE, WAITSTR)                                          \
    {                                                                                \
        short8 afr[4][2], bfr[2][2];                                                 \
        _Pragma("unroll") for (int i = 0; i < 4; ++i)                                \
            _Pragma("unroll") for (int ks = 0; ks < 2; ++ks)                         \
                afr[i][ks] = *(const short8*)(&As[buf][((wmf + (mh)*4 + i)*2 + ks)*512 + lid*8]); \
        _Pragma("unroll") for (int j = 0; j < 2; ++j)                                \
            _Pragma("unroll") for (int ks = 0; ks < 2; ++ks)                         \
                bfr[j][ks] = *(const short8*)(&Bs[buf][((wnf + (nh)*2 + j)*2 + ks)*512 + lid*8]); \
        STAGE;                                                                       \
        __builtin_amdgcn_s_barrier();                                                \
        asm volatile("s_waitcnt lgkmcnt(0)" ::: "memory");                           \
        __builtin_amdgcn_sched_barrier(0);                                           \
        __builtin_amdgcn_s_setprio(1);                                               \
        _Pragma("unroll") for (int i = 0; i < 4; ++i)                                \
            _Pragma("unroll") for (int j = 0; j < 2; ++j)                            \
                _Pragma("unroll") for (int ks = 0; ks < 2; ++ks)                     \
                    acc[(mh)*4 + i][(nh)*2 + j] = __builtin_amdgcn_mfma_f32_16x16x32_bf16( \
                        afr[i][ks], bfr[j][ks], acc[(mh)*4 + i][(nh)*2 + j], 0, 0, 0); \
        __builtin_amdgcn_s_setprio(0);                                               \
        asm volatile(WAITSTR ::: "memory");                                          \
        __builtin_amdgcn_s_barrier();                                                \
    }

    const int nk = K / 64;            // 2304/64 = 36
    const int niter = nk / 2;         // 18

    // prologue: all of b0 (tile 0), then b1.A-mh0 + b1.B-nh0 (tile 1)
    sAm0(0, 0); sBn0(0, 0); sAm1(0, 0); sBn1(0, 0);
    sAm0(1, 64); sBn0(1, 64);
    asm volatile("s_waitcnt vmcnt(4)" ::: "memory");   // first 8 glls (= all b0) done
    __builtin_amdgcn_s_barrier();

    for (int I = 0; I < niter - 1; ++I) {
        const int kc = I * 128;       // tile 2I at kc (b0), 2I+1 at kc+64 (b1)
        GPHASE(0, 0, 0, sAm1(1, kc + 64);,  "")
        GPHASE(0, 1, 0, sBn1(1, kc + 64);,  "")
        GPHASE(1, 0, 0, sAm0(0, kc + 128);, "")
        GPHASE(1, 1, 0, sBn0(0, kc + 128);, "s_waitcnt vmcnt(4)")
        GPHASE(0, 0, 1, sAm1(0, kc + 128);, "")
        GPHASE(0, 1, 1, sBn1(0, kc + 128);, "")
        GPHASE(1, 0, 1, sAm0(1, kc + 192);, "")
        GPHASE(1, 1, 1, sBn0(1, kc + 192);, "s_waitcnt vmcnt(4)")
    }
    // peeled last iteration: finish b1 (tile nk-1) in ph1/ph2, drain at ph4
    {
        const int kc = (niter - 1) * 128;
        GPHASE(0, 0, 0, sAm1(1, kc + 64);, "")
        GPHASE(0, 1, 0, sBn1(1, kc + 64);, "")
        GPHASE(1, 0, 0, {};,               "")
        GPHASE(1, 1, 0, {};,               "s_waitcnt vmcnt(0)")
        GPHASE(0, 0, 1, {};,               "")
        GPHASE(0, 1, 1, {};,               "")
        GPHASE(1, 0, 1, {};,               "")
        GPHASE(1, 1, 1, {};,               "")
    }
#undef GPHASE

    // C-write: rows m0 + (w>>2)*128 + mi*16 + quad*4 + rg; cols n0 + (w&3)*64 + nj*16 + n16
    #pragma unroll
    for (int mi = 0; mi < 8; ++mi) {
        #pragma unroll
        for (int nj = 0; nj < 4; ++nj) {
            int rbase = m0 + (w >> 2) * 128 + mi * 16 + quad * 4;
            int col   = n0 + (w & 3) * 64 + nj * 16 + n16;
            #pragma unroll
            for (int rg = 0; rg < 4; ++rg)
                store_c(C + (size_t)(rbase + rg) * N + col, acc[mi][nj][rg]);
        }
    }
}

// ---------------------------------------------------------------------------
// RoPE: read bf16 Q/K from fused QKV [S][4096], write Qb/Kb (SCALE folded).
// ---------------------------------------------------------------------------
__global__ __launch_bounds__(256) void rope_kernel(const unsigned short* __restrict__ QKV,
                                                   unsigned short* __restrict__ Qb,
                                                   unsigned short* __restrict__ Kb,
                                                   const int* __restrict__ pos_ids)
{
    int id   = blockIdx.x * 256 + threadIdx.x;   // S * 12 * 128 threads
    int d    = id & 127;
    int rest = id >> 7;
    int hh   = rest % 12;
    int i    = rest / 12;
    float pos = (float)pos_ids[i];
    float inv = __expf((float)d * (-9.210340371976184f / 128.0f));   // 10000^(-d/128)
    float ang = pos * inv;
    float sn, cs;
    sincosf(ang, &sn, &cs);
    if (hh < HQ) {
        const unsigned short* p = QKV + (size_t)i * QKVDIM + hh * D + d;
        float x0 = bf2f(p[0]), x1 = bf2f(p[128]);
        unsigned short* q = Qb + (size_t)i * QDIM + hh * D + d;
        q[0]   = (unsigned short)f2bf((x0 * cs - x1 * sn) * SCALE);
        q[128] = (unsigned short)f2bf((x1 * cs + x0 * sn) * SCALE);
    } else {
        const unsigned short* p = QKV + (size_t)i * QKVDIM + QDIM + (hh - HQ) * D + d;
        float x0 = bf2f(p[0]), x1 = bf2f(p[128]);
        unsigned short* k = Kb + (size_t)i * KVDIM + (hh - HQ) * D + d;
        k[0]   = (unsigned short)f2bf(x0 * cs - x1 * sn);
        k[128] = (unsigned short)f2bf(x1 * cs + x0 * sn);
    }
}

// ---------------------------------------------------------------------------
// V transpose: fused QKV [S][4096] cols 3072..4095 -> Vt [KVDIM][S] bf16.
// ---------------------------------------------------------------------------
__global__ __launch_bounds__(256) void transpose_v(const unsigned short* __restrict__ QKV,
                                                   unsigned short* __restrict__ Vt)
{
    __shared__ float tile[64][65];
    const int s0 = blockIdx.x * 64, d0 = blockIdx.y * 64;
    const int t = threadIdx.x;
    #pragma unroll
    for (int it = 0; it < 4; ++it) {
        int flat = it * 256 + t;
        int r  = flat >> 4;
        int c4 = (flat & 15) * 4;
        uint2 v = *(const uint2*)(QKV + (size_t)(s0 + r) * QKVDIM + (QDIM + KVDIM) + d0 + c4);
        tile[r][c4 + 0] = bf2f(v.x & 0xffffu); tile[r][c4 + 1] = bf2f(v.x >> 16);
        tile[r][c4 + 2] = bf2f(v.y & 0xffffu); tile[r][c4 + 3] = bf2f(v.y >> 16);
    }
    __syncthreads();
    #pragma unroll
    for (int it = 0; it < 4; ++it) {
        int flat = it * 256 + t;
        int dr  = flat >> 4;
        int sc4 = (flat & 15) * 4;
        uint2 o;
        o.x = f2bf(tile[sc4 + 0][dr]) | (f2bf(tile[sc4 + 1][dr]) << 16);
        o.y = f2bf(tile[sc4 + 2][dr]) | (f2bf(tile[sc4 + 3][dr]) << 16);
        *(uint2*)(Vt + (size_t)(d0 + dr) * S + s0 + sc4) = o;
    }
}

// ---------------------------------------------------------------------------
// MFMA flash attention: FIXED-MAX softmax + 64-key tiles + single-buffered
// LDS with T14 async-STAGE split (issue-early to regs / commit-late to LDS).
// Per iteration: vmcnt(0) -> commit regs->LDS -> barrier A (tile visible) ->
// issue next-tile loads (latency hides under full compute phase) -> QK^T ->
// softmax/P -> PV -> barrier B (reads done; next commit may overwrite).
// Halves the serial-chain events per key vs the 32-key double-buffer version.
// LDS = K 32K + V 32K + P 8K = 72K => 2 blocks/CU. Split-KV reverted (R7:
// proven no-op; time = avg work x per-iter latency, not max-CU tail).
// ---------------------------------------------------------------------------
__global__ __launch_bounds__(256, 2) void attn_kernel(const unsigned short* __restrict__ Qb,
                                                      const unsigned short* __restrict__ Kb,
                                                      const unsigned short* __restrict__ Vt,
                                                      unsigned short* __restrict__ O)
{
    __shared__ unsigned short Ks[32 * 512];   // frag f=nt*8+ks: K[key=nt*16+n16][k=ks*32+quad*8]
    __shared__ unsigned short Vs[32 * 512];   // frag f=dt*2+ks2: Vt[d=dt*16+n16][key=ks2*32+quad*8]
    __shared__ unsigned short Ps[4 * 1024];   // per-wave 2 frags: P[16 rows][64 keys]
    const int t = threadIdx.x;
    const int bid = blockIdx.x;
    const int b2 = bid & 255;
    const int h = b2 & 7, kvh = h >> 1;
    const int u = b2 >> 3;
    const int g = (bid < 256) ? u : 63 - u;
    const int i0 = g * 64;
    const int w = t >> 6, lid = t & 63, n16 = lid & 15, quad = lid >> 4;
    const int qbase = i0 + w * 16;
    unsigned short* Pw = Ps + w * 1024;

    uint4 kr[8], vr[8];   // reg-staged next tile (16 KiB/wave)

    // issue tile-j0 global loads into regs (8 K-frags + 8 V-frags per wave)
    auto issue = [&](int j0) {
        #pragma unroll
        for (int it = 0; it < 8; ++it) {
            int f = it * 4 + w;               // wave's K frag set
            int nt = f >> 3, ks = f & 7;
            kr[it] = *(const uint4*)(Kb + (size_t)(j0 + nt * 16 + n16) * KVDIM + kvh * D + ks * 32 + quad * 8);
        }
        #pragma unroll
        for (int it = 0; it < 8; ++it) {
            int f = it * 4 + w;               // wave's V frag set
            int dt = f >> 1, ks2 = f & 1;
            vr[it] = *(const uint4*)(Vt + (size_t)(kvh * D + dt * 16 + n16) * S + j0 + ks2 * 32 + quad * 8);
        }
    };
    // commit staged regs into LDS (16 x ds_write_b128 per wave)
    auto commit = [&]() {
        #pragma unroll
        for (int it = 0; it < 8; ++it) {
            int f = it * 4 + w;
            *(uint4*)(&Ks[f * 512 + lid * 8]) = kr[it];
        }
        #pragma unroll
        for (int it = 0; it < 8; ++it) {
            int f = it * 4 + w;
            *(uint4*)(&Vs[f * 512 + lid * 8]) = vr[it];
        }
    };

    // Q A-frags in registers: qf[ks], 16 rows per wave
    short8 qf[8];
    #pragma unroll
    for (int ks = 0; ks < 8; ++ks)
        qf[ks] = *(const short8*)(Qb + (size_t)(qbase + n16) * QDIM + h * D + ks * 32 + quad * 8);

    float lacc[4] = {0.f, 0.f, 0.f, 0.f};
    f32x4 Oacc[16] = {};

    const int jt_min = (i0 >= SW) ? ((i0 - (SW - 1)) >> 6) : 0;
    const int jt_max = (i0 + 63) >> 6;

    issue(jt_min * 64);

    for (int jt = jt_min; jt <= jt_max; ++jt) {
        const int j0 = jt * 64;
        asm volatile("s_waitcnt vmcnt(0)" ::: "memory");   // own tile-j loads in regs
        commit();                                          // regs -> LDS
        __syncthreads();                                   // barrier A: tile j visible
        if (jt < jt_max) issue((jt + 1) * 64);             // next-tile loads under compute

        // ---- S = Q K^T (32 MFMA)
        f32x4 sc[4] = {};
        __builtin_amdgcn_s_setprio(1);
        #pragma unroll
        for (int ks = 0; ks < 8; ++ks) {
            #pragma unroll
            for (int nt = 0; nt < 4; ++nt) {
                short8 kf = *(const short8*)(&Ks[(nt * 8 + ks) * 512 + lid * 8]);
                sc[nt] = __builtin_amdgcn_mfma_f32_16x16x32_bf16(qf[ks], kf, sc[nt], 0, 0, 0);
            }
        }
        __builtin_amdgcn_s_setprio(0);

        // ---- fused softcap + fixed-max softmax: p = exp(-100/(exp(2s/50)+1))
        #pragma unroll
        for (int nt = 0; nt < 4; ++nt) {
            int j = j0 + nt * 16 + n16;
            #pragma unroll
            for (int rg = 0; rg < 4; ++rg) {
                int iq = qbase + quad * 4 + rg;
                float e = __expf(sc[nt][rg] * (2.0f / SOFTCAP));
                float p = __expf(-100.0f * __builtin_amdgcn_rcpf(e + 1.0f));
                bool ok = (j <= iq) && (iq - j < SW);
                p = ok ? p : 0.0f;
                lacc[rg] += p;
                // A-frag (per 32-key half ks2=nt>>1): lane' = row + 16*((nt&1)*2 + (n16>>3)), elem = n16&7
                Pw[(nt >> 1) * 512 + (quad * 4 + rg + 16 * ((nt & 1) * 2 + (n16 >> 3))) * 8 + (n16 & 7)]
                    = (unsigned short)f2bf(p);
            }
        }

        asm volatile("s_waitcnt lgkmcnt(0)" ::: "memory");   // P writes visible (wave-private)

        // ---- O += P V (32 MFMA)
        short8 pf0 = *(const short8*)(Pw + lid * 8);
        short8 pf1 = *(const short8*)(Pw + 512 + lid * 8);
        __builtin_amdgcn_s_setprio(1);
        #pragma unroll
        for (int dt = 0; dt < 16; ++dt) {
            short8 vf0 = *(const short8*)(&Vs[(dt * 2 + 0) * 512 + lid * 8]);
            Oacc[dt] = __builtin_amdgcn_mfma_f32_16x16x32_bf16(pf0, vf0, Oacc[dt], 0, 0, 0);
            short8 vf1 = *(const short8*)(&Vs[(dt * 2 + 1) * 512 + lid * 8]);
            Oacc[dt] = __builtin_amdgcn_mfma_f32_16x16x32_bf16(pf1, vf1, Oacc[dt], 0, 0, 0);
        }
        __builtin_amdgcn_s_setprio(0);

        __syncthreads();                                   // barrier B: reads of tile j done
    }

    // final row-sum reduce across the 16 key-lanes (once)
    float linv[4];
    #pragma unroll
    for (int rg = 0; rg < 4; ++rg) {
        float rs = lacc[rg];
        rs += __shfl_xor(rs, 1); rs += __shfl_xor(rs, 2);
        rs += __shfl_xor(rs, 4); rs += __shfl_xor(rs, 8);
        linv[rg] = 1.0f / rs;
    }
    #pragma unroll
    for (int dt = 0; dt < 16; ++dt) {
        int col = h * D + dt * 16 + n16;
        #pragma unroll
        for (int rg = 0; rg < 4; ++rg) {
            int row = qbase + quad * 4 + rg;
            O[(size_t)row * QDIM + col] = (unsigned short)f2bf(Oacc[dt][rg] * linv[rg]);
        }
    }
}

extern "C" void kernel_launch(void* const* d_in, const int* in_sizes, int n_in,
                              void* d_out, int out_size, void* d_ws, size_t ws_size,
                              hipStream_t stream) {
    const float* hidden = (const float*)d_in[0];
    // d_in[1] = attention_mask: recomputed analytically, not read
    const float* Wq = (const float*)d_in[2];
    const float* Wk = (const float*)d_in[3];
    const float* Wv = (const float*)d_in[4];
    const float* Wo = (const float*)d_in[5];
    const int* pos = (const int*)d_in[6];
    float* out = (float*)d_out;

    // workspace layout (85 MiB total, aggressive aliasing):
    //  [0,18M)   Hb  [S][2304] bf16            -> dead after QKV GEMM; Qb [S][2048] aliases
    //  [18,37M)  Wqkv bf16 (19M)               -> dead after QKV GEMM; Wo bf16 (9M) aliases
    //  [37,69M)  QKVf [S][4096] bf16 (32M)     -> dead after rope+transpose; Oa (16M) aliases
    //  [69,77M)  Kb  [S][1024] bf16 (8M)
    //  [77,85M)  Vt  [1024][S] bf16 (8M)
    char* ws = (char*)d_ws;
    unsigned short* Hb   = (unsigned short*)(ws);
    unsigned short* Qb   = (unsigned short*)(ws);
    unsigned short* Wqkv = (unsigned short*)(ws + (size_t)(18 << 20));
    unsigned short* QKVf = (unsigned short*)(ws + (size_t)(37 << 20));
    unsigned short* Oa   = (unsigned short*)(ws + (size_t)(37 << 20));
    unsigned short* Kb   = (unsigned short*)(ws + (size_t)(69 << 20));
    unsigned short* Vt   = (unsigned short*)(ws + (size_t)(77 << 20));

    cvt_bf16<<<(S * HID) / 1024, 256, 0, stream>>>(hidden, Hb);
    cvt_bf16<<<(QDIM * HID) / 1024, 256, 0, stream>>>(Wq, Wqkv);
    cvt_bf16<<<(KVDIM * HID) / 1024, 256, 0, stream>>>(Wk, Wqkv + (size_t)QDIM * HID);
    cvt_bf16<<<(KVDIM * HID) / 1024, 256, 0, stream>>>(Wv, Wqkv + (size_t)(QDIM + KVDIM) * HID);

    // fused QKV projection on the 256^2 8-phase kernel: grid 16x16 = 256 blocks
    bf16_gemm_8ph<<<256, 512, 0, stream>>>(Hb, Wqkv, QKVf, S, QKVDIM, HID);

    rope_kernel<<<(S * 12 * 128) / 256, 256, 0, stream>>>(QKVf, Qb, Kb, pos);
    transpose_v<<<dim3(S / 64, KVDIM / 64), 256, 0, stream>>>(QKVf, Vt);

    attn_kernel<<<512, 256, 0, stream>>>(Qb, Kb, Vt, Oa);

    cvt_bf16<<<(HID * QDIM) / 1024, 256, 0, stream>>>(Wo, Wqkv);
    bf16_gemm_bt<float><<<dim3(HID / 128, S / 128), 256, 0, stream>>>(Oa, Wqkv, out, S, HID, QDIM);
}

// Round 9
// 553.662 us; speedup vs baseline: 1.4463x; 1.4463x over previous
//
#include <hip/hip_runtime.h>
#include <hip/hip_bf16.h>
#include <math.h>

#define S 4096
#define HQ 8
#define NKVH 4
#define D 256
#define HID 2304
#define SW 2048
#define QDIM 2048
#define KVDIM 1024
#define QKVDIM 4096          // fused Q(2048) | K(1024) | V(1024)
#define SCALE 0.0625f
#define SOFTCAP 50.0f

typedef __attribute__((ext_vector_type(4))) float f32x4;
typedef __attribute__((ext_vector_type(8))) short short8;   // 8 bf16 = 4 VGPRs (MFMA A/B frag)

__device__ __forceinline__ float bf2f(unsigned v) { return __uint_as_float(v << 16); }
__device__ __forceinline__ unsigned f2bf(float f) {
    unsigned u = __float_as_uint(f);
    return (u + 0x7fffu + ((u >> 16) & 1u)) >> 16;   // round-to-nearest-even
}

__device__ __forceinline__ void store_c(float* p, float v) { *p = v; }
__device__ __forceinline__ void store_c(unsigned short* p, float v) { *p = (unsigned short)f2bf(v); }

// async global->LDS, 16B per lane; lds dst is wave-uniform base (HW adds lane*16)
__device__ __forceinline__ void glls16(const void* g, void* l) {
    __builtin_amdgcn_global_load_lds(
        (const __attribute__((address_space(1))) unsigned int*)g,
        (__attribute__((address_space(3))) unsigned int*)l, 16, 0, 0);
}

// ---------------------------------------------------------------------------
// fp32 -> bf16 elementwise (float4 per thread)
// ---------------------------------------------------------------------------
__global__ __launch_bounds__(256) void cvt_bf16(const float* __restrict__ in,
                                                unsigned short* __restrict__ out)
{
    int i = blockIdx.x * 256 + threadIdx.x;
    float4 v = ((const float4*)in)[i];
    uint2 o;
    o.x = f2bf(v.x) | (f2bf(v.y) << 16);
    o.y = f2bf(v.z) | (f2bf(v.w) << 16);
    ((uint2*)out)[i] = o;
}

// ---------------------------------------------------------------------------
// 128x128-tile GEMM (verified m97-style structure) — kept for O-projection.
// C[M][N] = A[M][K] @ B[N][K]^T, bf16 in, fp32 accumulate, TC out.
// ---------------------------------------------------------------------------
template <typename TC>
__global__ __launch_bounds__(256) void bf16_gemm_bt(const unsigned short* __restrict__ A,
                                                    const unsigned short* __restrict__ B,
                                                    TC* __restrict__ C,
                                                    int M, int N, int K)
{
    __shared__ unsigned short As[2][16 * 512];   // 16 frags x 1 KiB per buffer
    __shared__ unsigned short Bs[2][16 * 512];
    const int t = threadIdx.x;

    // bijective XCD swizzle of the flattened tile id
    const int nbx = gridDim.x;
    const int nwg = nbx * gridDim.y;
    int flat = blockIdx.y * nbx + blockIdx.x;
    const int q8 = nwg >> 3, r8 = nwg & 7;
    const int xcd = flat & 7, orig = flat >> 3;
    const int wg = (xcd < r8 ? xcd * (q8 + 1) : r8 * (q8 + 1) + (xcd - r8) * q8) + orig;
    // grouped raster: bands of 8 m-tiles, n sweeps within a band
    const int band = wg / (8 * nbx);
    const int rem  = wg - band * 8 * nbx;
    const int m0 = (band * 8 + (rem & 7)) * 128;
    const int n0 = (rem >> 3) * 128;

    const int w = t >> 6, lid = t & 63, n16 = lid & 15, quad = lid >> 4;
    const int wm = (w >> 1) * 64, wn = (w & 1) * 64;

    f32x4 acc[4][4] = {};

    auto stage = [&](int buf, int k0) {
        #pragma unroll
        for (int it = 0; it < 4; ++it) {
            int f  = it * 4 + w;              // wave-uniform frag id 0..15
            int fm = f >> 1, fk = f & 1;
            const size_t goff = (size_t)(fm * 16 + n16) * K + k0 + fk * 32 + quad * 8;
            glls16(A + (size_t)m0 * K + goff, &As[buf][f * 512]);
            glls16(B + (size_t)n0 * K + goff, &Bs[buf][f * 512]);
        }
    };

    const int nk = K / 64;
    stage(0, 0);
    int cur = 0;
    for (int kk = 0; kk < nk; ++kk) {
        asm volatile("s_waitcnt vmcnt(0)" ::: "memory");   // own staging done
        __syncthreads();                                   // everyone's visible
        if (kk + 1 < nk) stage(cur ^ 1, (kk + 1) * 64);    // prefetch next panel
        #pragma unroll
        for (int ks = 0; ks < 2; ++ks) {
            short8 af[4], bfr[4];
            #pragma unroll
            for (int x = 0; x < 4; ++x) {
                af[x]  = *(const short8*)(&As[cur][(((wm >> 4) + x) * 2 + ks) * 512 + lid * 8]);
                bfr[x] = *(const short8*)(&Bs[cur][(((wn >> 4) + x) * 2 + ks) * 512 + lid * 8]);
            }
            __builtin_amdgcn_s_setprio(1);
            #pragma unroll
            for (int i = 0; i < 4; ++i)
                #pragma unroll
                for (int j = 0; j < 4; ++j)
                    acc[i][j] = __builtin_amdgcn_mfma_f32_16x16x32_bf16(af[i], bfr[j], acc[i][j], 0, 0, 0);
            __builtin_amdgcn_s_setprio(0);
        }
        cur ^= 1;
    }

    #pragma unroll
    for (int i = 0; i < 4; ++i) {
        #pragma unroll
        for (int j = 0; j < 4; ++j) {
            int rbase = m0 + wm + i * 16 + quad * 4;
            int col   = n0 + wn + j * 16 + n16;
            #pragma unroll
            for (int rg = 0; rg < 4; ++rg)
                store_c(C + (size_t)(rbase + rg) * N + col, acc[i][j][rg]);
        }
    }
}

// ---------------------------------------------------------------------------
// 256x256-tile 8-phase GEMM (T3+T4: counted vmcnt), bf16->bf16. 512 threads =
// 8 waves (2m x 4n), per-wave output 128x64, BK=64, 2 K-tiles/iteration.
// Fragment-major LDS => conflict-free without byte-swizzle. LDS = 128 KiB.
// Staging schedule + per-phase vmcnt ledger as verified in R6 (passing).
// ---------------------------------------------------------------------------
__global__ __launch_bounds__(512, 2) void bf16_gemm_8ph(const unsigned short* __restrict__ A,
                                                        const unsigned short* __restrict__ B,
                                                        unsigned short* __restrict__ C,
                                                        int M, int N, int K)
{
    __shared__ unsigned short As[2][32 * 512];   // 32 frags (16 m x 2 ks) x 1 KiB
    __shared__ unsigned short Bs[2][32 * 512];   // 32 frags (16 n x 2 ks) x 1 KiB
    const int t = threadIdx.x;
    const int w = t >> 6, lid = t & 63, n16 = lid & 15, quad = lid >> 4;

    // XCD chunk swizzle (grid = 256, 32 blocks/XCD contiguous)
    const int flat = blockIdx.x;
    const int wg = (flat & 7) * 32 + (flat >> 3);
    const int m0 = (wg >> 4) * 256, n0 = (wg & 15) * 256;

    const int wmf = (w >> 2) * 8;             // wave m-frag base (0 or 8)
    const int wnf = (w & 3) * 4;              // wave n-frag base (0,4,8,12)
    const int fnw = (w >> 1) * 4 + (w & 1);   // B nh0 staging frag for this wave

    f32x4 acc[8][4] = {};

    auto stageA = [&](int buf, int k0, int fm) {
        glls16(A + (size_t)(m0 + fm * 16 + n16) * K + k0 + quad * 8,
               &As[buf][(fm * 2 + 0) * 512]);
        glls16(A + (size_t)(m0 + fm * 16 + n16) * K + k0 + 32 + quad * 8,
               &As[buf][(fm * 2 + 1) * 512]);
    };
    auto stageB = [&](int buf, int k0, int fn) {
        glls16(B + (size_t)(n0 + fn * 16 + n16) * K + k0 + quad * 8,
               &Bs[buf][(fn * 2 + 0) * 512]);
        glls16(B + (size_t)(n0 + fn * 16 + n16) * K + k0 + 32 + quad * 8,
               &Bs[buf][(fn * 2 + 1) * 512]);
    };
    // bijective wave->frag assignments matching the read sets:
    auto sAm0 = [&](int buf, int k0){ stageA(buf, k0, (w & 3) + (w >> 2) * 8); };      // {0..3, 8..11}
    auto sAm1 = [&](int buf, int k0){ stageA(buf, k0, 4 + (w & 3) + (w >> 2) * 8); };  // {4..7, 12..15}
    auto sBn0 = [&](int buf, int k0){ stageB(buf, k0, fnw); };                          // {0,1,4,5,8,9,12,13}
    auto sBn1 = [&](int buf, int k0){ stageB(buf, k0, fnw + 2); };                      // {2,3,6,7,10,11,14,15}

#define GPHASE(mh, nh, buf, STAGE, WAITSTR)                                          \
    {                                                                                \
        short8 afr[4][2], bfr[2][2];                                                 \
        _Pragma("unroll") for (int i = 0; i < 4; ++i)                                \
            _Pragma("unroll") for (int ks = 0; ks < 2; ++ks)                         \
                afr[i][ks] = *(const short8*)(&As[buf][((wmf + (mh)*4 + i)*2 + ks)*512 + lid*8]); \
        _Pragma("unroll") for (int j = 0; j < 2; ++j)                                \
            _Pragma("unroll") for (int ks = 0; ks < 2; ++ks)                         \
                bfr[j][ks] = *(const short8*)(&Bs[buf][((wnf + (nh)*2 + j)*2 + ks)*512 + lid*8]); \
        STAGE;                                                                       \
        __builtin_amdgcn_s_barrier();                                                \
        asm volatile("s_waitcnt lgkmcnt(0)" ::: "memory");                           \
        __builtin_amdgcn_sched_barrier(0);                                           \
        __builtin_amdgcn_s_setprio(1);                                               \
        _Pragma("unroll") for (int i = 0; i < 4; ++i)                                \
            _Pragma("unroll") for (int j = 0; j < 2; ++j)                            \
                _Pragma("unroll") for (int ks = 0; ks < 2; ++ks)                     \
                    acc[(mh)*4 + i][(nh)*2 + j] = __builtin_amdgcn_mfma_f32_16x16x32_bf16( \
                        afr[i][ks], bfr[j][ks], acc[(mh)*4 + i][(nh)*2 + j], 0, 0, 0); \
        __builtin_amdgcn_s_setprio(0);                                               \
        asm volatile(WAITSTR ::: "memory");                                          \
        __builtin_amdgcn_s_barrier();                                                \
    }

    const int nk = K / 64;            // 2304/64 = 36
    const int niter = nk / 2;         // 18

    // prologue: all of b0 (tile 0), then b1.A-mh0 + b1.B-nh0 (tile 1)
    sAm0(0, 0); sBn0(0, 0); sAm1(0, 0); sBn1(0, 0);
    sAm0(1, 64); sBn0(1, 64);
    asm volatile("s_waitcnt vmcnt(4)" ::: "memory");   // first 8 glls (= all b0) done
    __builtin_amdgcn_s_barrier();

    for (int I = 0; I < niter - 1; ++I) {
        const int kc = I * 128;       // tile 2I at kc (b0), 2I+1 at kc+64 (b1)
        GPHASE(0, 0, 0, sAm1(1, kc + 64);,  "")
        GPHASE(0, 1, 0, sBn1(1, kc + 64);,  "")
        GPHASE(1, 0, 0, sAm0(0, kc + 128);, "")
        GPHASE(1, 1, 0, sBn0(0, kc + 128);, "s_waitcnt vmcnt(4)")
        GPHASE(0, 0, 1, sAm1(0, kc + 128);, "")
        GPHASE(0, 1, 1, sBn1(0, kc + 128);, "")
        GPHASE(1, 0, 1, sAm0(1, kc + 192);, "")
        GPHASE(1, 1, 1, sBn0(1, kc + 192);, "s_waitcnt vmcnt(4)")
    }
    // peeled last iteration: finish b1 (tile nk-1) in ph1/ph2, drain at ph4
    {
        const int kc = (niter - 1) * 128;
        GPHASE(0, 0, 0, sAm1(1, kc + 64);, "")
        GPHASE(0, 1, 0, sBn1(1, kc + 64);, "")
        GPHASE(1, 0, 0, {};,               "")
        GPHASE(1, 1, 0, {};,               "s_waitcnt vmcnt(0)")
        GPHASE(0, 0, 1, {};,               "")
        GPHASE(0, 1, 1, {};,               "")
        GPHASE(1, 0, 1, {};,               "")
        GPHASE(1, 1, 1, {};,               "")
    }
#undef GPHASE

    // C-write: rows m0 + (w>>2)*128 + mi*16 + quad*4 + rg; cols n0 + (w&3)*64 + nj*16 + n16
    #pragma unroll
    for (int mi = 0; mi < 8; ++mi) {
        #pragma unroll
        for (int nj = 0; nj < 4; ++nj) {
            int rbase = m0 + (w >> 2) * 128 + mi * 16 + quad * 4;
            int col   = n0 + (w & 3) * 64 + nj * 16 + n16;
            #pragma unroll
            for (int rg = 0; rg < 4; ++rg)
                store_c(C + (size_t)(rbase + rg) * N + col, acc[mi][nj][rg]);
        }
    }
}

// ---------------------------------------------------------------------------
// RoPE: read bf16 Q/K from fused QKV [S][4096], write Qb/Kb (SCALE folded).
// ---------------------------------------------------------------------------
__global__ __launch_bounds__(256) void rope_kernel(const unsigned short* __restrict__ QKV,
                                                   unsigned short* __restrict__ Qb,
                                                   unsigned short* __restrict__ Kb,
                                                   const int* __restrict__ pos_ids)
{
    int id   = blockIdx.x * 256 + threadIdx.x;   // S * 12 * 128 threads
    int d    = id & 127;
    int rest = id >> 7;
    int hh   = rest % 12;
    int i    = rest / 12;
    float pos = (float)pos_ids[i];
    float inv = __expf((float)d * (-9.210340371976184f / 128.0f));   // 10000^(-d/128)
    float ang = pos * inv;
    float sn, cs;
    sincosf(ang, &sn, &cs);
    if (hh < HQ) {
        const unsigned short* p = QKV + (size_t)i * QKVDIM + hh * D + d;
        float x0 = bf2f(p[0]), x1 = bf2f(p[128]);
        unsigned short* q = Qb + (size_t)i * QDIM + hh * D + d;
        q[0]   = (unsigned short)f2bf((x0 * cs - x1 * sn) * SCALE);
        q[128] = (unsigned short)f2bf((x1 * cs + x0 * sn) * SCALE);
    } else {
        const unsigned short* p = QKV + (size_t)i * QKVDIM + QDIM + (hh - HQ) * D + d;
        float x0 = bf2f(p[0]), x1 = bf2f(p[128]);
        unsigned short* k = Kb + (size_t)i * KVDIM + (hh - HQ) * D + d;
        k[0]   = (unsigned short)f2bf(x0 * cs - x1 * sn);
        k[128] = (unsigned short)f2bf(x1 * cs + x0 * sn);
    }
}

// ---------------------------------------------------------------------------
// V transpose: fused QKV [S][4096] cols 3072..4095 -> Vt [KVDIM][S] bf16.
// ---------------------------------------------------------------------------
__global__ __launch_bounds__(256) void transpose_v(const unsigned short* __restrict__ QKV,
                                                   unsigned short* __restrict__ Vt)
{
    __shared__ float tile[64][65];
    const int s0 = blockIdx.x * 64, d0 = blockIdx.y * 64;
    const int t = threadIdx.x;
    #pragma unroll
    for (int it = 0; it < 4; ++it) {
        int flat = it * 256 + t;
        int r  = flat >> 4;
        int c4 = (flat & 15) * 4;
        uint2 v = *(const uint2*)(QKV + (size_t)(s0 + r) * QKVDIM + (QDIM + KVDIM) + d0 + c4);
        tile[r][c4 + 0] = bf2f(v.x & 0xffffu); tile[r][c4 + 1] = bf2f(v.x >> 16);
        tile[r][c4 + 2] = bf2f(v.y & 0xffffu); tile[r][c4 + 3] = bf2f(v.y >> 16);
    }
    __syncthreads();
    #pragma unroll
    for (int it = 0; it < 4; ++it) {
        int flat = it * 256 + t;
        int dr  = flat >> 4;
        int sc4 = (flat & 15) * 4;
        uint2 o;
        o.x = f2bf(tile[sc4 + 0][dr]) | (f2bf(tile[sc4 + 1][dr]) << 16);
        o.y = f2bf(tile[sc4 + 2][dr]) | (f2bf(tile[sc4 + 3][dr]) << 16);
        *(uint2*)(Vt + (size_t)(d0 + dr) * S + s0 + sc4) = o;
    }
}

// ---------------------------------------------------------------------------
// MFMA flash attention: FIXED-MAX softmax + 64-key tiles + single-buffered
// LDS with T14 async-STAGE split. R8 RETRY with rule-#20 fix: staging in
// SIXTEEN NAMED uint4 registers (kr0..kr7, vr0..vr7) via macros — no arrays,
// no lambdas, no address capture => guaranteed VGPR residency (R8's lambda-
// captured arrays spilled to scratch: WRITE_SIZE 763 MB, 2.5x regression).
// Per iteration: vmcnt(0) -> commit regs->LDS -> barrier A -> issue next-tile
// loads (hide under compute) -> QK^T -> softmax/P -> PV -> barrier B.
// LDS = K 32K + V 32K + P 8K = 72K => 2 blocks/CU.
// ---------------------------------------------------------------------------
__global__ __launch_bounds__(256, 2) void attn_kernel(const unsigned short* __restrict__ Qb,
                                                      const unsigned short* __restrict__ Kb,
                                                      const unsigned short* __restrict__ Vt,
                                                      unsigned short* __restrict__ O)
{
    __shared__ unsigned short Ks[32 * 512];   // frag f=nt*8+ks: K[key=nt*16+n16][k=ks*32+quad*8]
    __shared__ unsigned short Vs[32 * 512];   // frag f=dt*2+ks2: Vt[d=dt*16+n16][key=ks2*32+quad*8]
    __shared__ unsigned short Ps[4 * 1024];   // per-wave 2 frags: P[16 rows][64 keys]
    const int t = threadIdx.x;
    const int bid = blockIdx.x;
    const int b2 = bid & 255;
    const int h = b2 & 7, kvh = h >> 1;
    const int u = b2 >> 3;
    const int g = (bid < 256) ? u : 63 - u;
    const int i0 = g * 64;
    const int w = t >> 6, lid = t & 63, n16 = lid & 15, quad = lid >> 4;
    const int qbase = i0 + w * 16;
    unsigned short* Pw = Ps + w * 1024;

    // per-wave K/V base addresses (frag f = it*4 + w)
    const unsigned short* Kbase = Kb + kvh * D + quad * 8;
    const unsigned short* Vbase = Vt + (size_t)(kvh * D + n16) * S + quad * 8;

    uint4 kr0, kr1, kr2, kr3, kr4, kr5, kr6, kr7;
    uint4 vr0, vr1, vr2, vr3, vr4, vr5, vr6, vr7;

// f = IT*4+w; K frag: nt=f>>3, ks=f&7 -> row j0+nt*16+n16, col ks*32
#define KADDR(J0, IT) (Kbase + (size_t)((J0) + (((IT)*4 + w) >> 3) * 16 + n16) * KVDIM + (((IT)*4 + w) & 7) * 32)
// V frag: dt=f>>1, ks2=f&1 -> row dt*16+n16 (folded in Vbase), col j0+ks2*32
#define VADDR(J0, IT) (Vbase + (size_t)((((IT)*4 + w) >> 1) * 16) * S + (J0) + (((IT)*4 + w) & 1) * 32)
#define ISSUE(J0) do { const int _j = (J0);                                   \
        kr0 = *(const uint4*)KADDR(_j, 0); kr1 = *(const uint4*)KADDR(_j, 1); \
        kr2 = *(const uint4*)KADDR(_j, 2); kr3 = *(const uint4*)KADDR(_j, 3); \
        kr4 = *(const uint4*)KADDR(_j, 4); kr5 = *(const uint4*)KADDR(_j, 5); \
        kr6 = *(const uint4*)KADDR(_j, 6); kr7 = *(const uint4*)KADDR(_j, 7); \
        vr0 = *(const uint4*)VADDR(_j, 0); vr1 = *(const uint4*)VADDR(_j, 1); \
        vr2 = *(const uint4*)VADDR(_j, 2); vr3 = *(const uint4*)VADDR(_j, 3); \
        vr4 = *(const uint4*)VADDR(_j, 4); vr5 = *(const uint4*)VADDR(_j, 5); \
        vr6 = *(const uint4*)VADDR(_j, 6); vr7 = *(const uint4*)VADDR(_j, 7); \
    } while (0)
#define COMMIT() do {                                                          \
        *(uint4*)(&Ks[(0*4 + w) * 512 + lid * 8]) = kr0;                       \
        *(uint4*)(&Ks[(1*4 + w) * 512 + lid * 8]) = kr1;                       \
        *(uint4*)(&Ks[(2*4 + w) * 512 + lid * 8]) = kr2;                       \
        *(uint4*)(&Ks[(3*4 + w) * 512 + lid * 8]) = kr3;                       \
        *(uint4*)(&Ks[(4*4 + w) * 512 + lid * 8]) = kr4;                       \
        *(uint4*)(&Ks[(5*4 + w) * 512 + lid * 8]) = kr5;                       \
        *(uint4*)(&Ks[(6*4 + w) * 512 + lid * 8]) = kr6;                       \
        *(uint4*)(&Ks[(7*4 + w) * 512 + lid * 8]) = kr7;                       \
        *(uint4*)(&Vs[(0*4 + w) * 512 + lid * 8]) = vr0;                       \
        *(uint4*)(&Vs[(1*4 + w) * 512 + lid * 8]) = vr1;                       \
        *(uint4*)(&Vs[(2*4 + w) * 512 + lid * 8]) = vr2;                       \
        *(uint4*)(&Vs[(3*4 + w) * 512 + lid * 8]) = vr3;                       \
        *(uint4*)(&Vs[(4*4 + w) * 512 + lid * 8]) = vr4;                       \
        *(uint4*)(&Vs[(5*4 + w) * 512 + lid * 8]) = vr5;                       \
        *(uint4*)(&Vs[(6*4 + w) * 512 + lid * 8]) = vr6;                       \
        *(uint4*)(&Vs[(7*4 + w) * 512 + lid * 8]) = vr7;                       \
    } while (0)

    // Q A-frags in registers: qf[ks], 16 rows per wave
    short8 qf[8];
    #pragma unroll
    for (int ks = 0; ks < 8; ++ks)
        qf[ks] = *(const short8*)(Qb + (size_t)(qbase + n16) * QDIM + h * D + ks * 32 + quad * 8);

    float lacc[4] = {0.f, 0.f, 0.f, 0.f};
    f32x4 Oacc[16] = {};

    const int jt_min = (i0 >= SW) ? ((i0 - (SW - 1)) >> 6) : 0;
    const int jt_max = (i0 + 63) >> 6;

    ISSUE(jt_min * 64);

    for (int jt = jt_min; jt <= jt_max; ++jt) {
        const int j0 = jt * 64;
        asm volatile("s_waitcnt vmcnt(0)" ::: "memory");   // own tile-j loads in regs
        COMMIT();                                          // regs -> LDS
        __syncthreads();                                   // barrier A: tile j visible
        if (jt < jt_max) ISSUE((jt + 1) * 64);             // next-tile loads under compute

        // ---- S = Q K^T (32 MFMA)
        f32x4 sc[4] = {};
        __builtin_amdgcn_s_setprio(1);
        #pragma unroll
        for (int ks = 0; ks < 8; ++ks) {
            #pragma unroll
            for (int nt = 0; nt < 4; ++nt) {
                short8 kf = *(const short8*)(&Ks[(nt * 8 + ks) * 512 + lid * 8]);
                sc[nt] = __builtin_amdgcn_mfma_f32_16x16x32_bf16(qf[ks], kf, sc[nt], 0, 0, 0);
            }
        }
        __builtin_amdgcn_s_setprio(0);

        // ---- fused softcap + fixed-max softmax: p = exp(-100/(exp(2s/50)+1))
        #pragma unroll
        for (int nt = 0; nt < 4; ++nt) {
            int j = j0 + nt * 16 + n16;
            #pragma unroll
            for (int rg = 0; rg < 4; ++rg) {
                int iq = qbase + quad * 4 + rg;
                float e = __expf(sc[nt][rg] * (2.0f / SOFTCAP));
                float p = __expf(-100.0f * __builtin_amdgcn_rcpf(e + 1.0f));
                bool ok = (j <= iq) && (iq - j < SW);
                p = ok ? p : 0.0f;
                lacc[rg] += p;
                // A-frag (32-key half ks2=nt>>1): lane' = row + 16*((nt&1)*2 + (n16>>3)), elem = n16&7
                Pw[(nt >> 1) * 512 + (quad * 4 + rg + 16 * ((nt & 1) * 2 + (n16 >> 3))) * 8 + (n16 & 7)]
                    = (unsigned short)f2bf(p);
            }
        }

        asm volatile("s_waitcnt lgkmcnt(0)" ::: "memory");   // P writes visible (wave-private)

        // ---- O += P V (32 MFMA)
        short8 pf0 = *(const short8*)(Pw + lid * 8);
        short8 pf1 = *(const short8*)(Pw + 512 + lid * 8);
        __builtin_amdgcn_s_setprio(1);
        #pragma unroll
        for (int dt = 0; dt < 16; ++dt) {
            short8 vf0 = *(const short8*)(&Vs[(dt * 2 + 0) * 512 + lid * 8]);
            Oacc[dt] = __builtin_amdgcn_mfma_f32_16x16x32_bf16(pf0, vf0, Oacc[dt], 0, 0, 0);
            short8 vf1 = *(const short8*)(&Vs[(dt * 2 + 1) * 512 + lid * 8]);
            Oacc[dt] = __builtin_amdgcn_mfma_f32_16x16x32_bf16(pf1, vf1, Oacc[dt], 0, 0, 0);
        }
        __builtin_amdgcn_s_setprio(0);

        __syncthreads();                                   // barrier B: reads of tile j done
    }
#undef KADDR
#undef VADDR
#undef ISSUE
#undef COMMIT

    // final row-sum reduce across the 16 key-lanes (once)
    float linv[4];
    #pragma unroll
    for (int rg = 0; rg < 4; ++rg) {
        float rs = lacc[rg];
        rs += __shfl_xor(rs, 1); rs += __shfl_xor(rs, 2);
        rs += __shfl_xor(rs, 4); rs += __shfl_xor(rs, 8);
        linv[rg] = 1.0f / rs;
    }
    #pragma unroll
    for (int dt = 0; dt < 16; ++dt) {
        int col = h * D + dt * 16 + n16;
        #pragma unroll
        for (int rg = 0; rg < 4; ++rg) {
            int row = qbase + quad * 4 + rg;
            O[(size_t)row * QDIM + col] = (unsigned short)f2bf(Oacc[dt][rg] * linv[rg]);
        }
    }
}

extern "C" void kernel_launch(void* const* d_in, const int* in_sizes, int n_in,
                              void* d_out, int out_size, void* d_ws, size_t ws_size,
                              hipStream_t stream) {
    const float* hidden = (const float*)d_in[0];
    // d_in[1] = attention_mask: recomputed analytically, not read
    const float* Wq = (const float*)d_in[2];
    const float* Wk = (const float*)d_in[3];
    const float* Wv = (const float*)d_in[4];
    const float* Wo = (const float*)d_in[5];
    const int* pos = (const int*)d_in[6];
    float* out = (float*)d_out;

    // workspace layout (85 MiB total, aggressive aliasing):
    //  [0,18M)   Hb  [S][2304] bf16            -> dead after QKV GEMM; Qb [S][2048] aliases
    //  [18,37M)  Wqkv bf16 (19M)               -> dead after QKV GEMM; Wo bf16 (9M) aliases
    //  [37,69M)  QKVf [S][4096] bf16 (32M)     -> dead after rope+transpose; Oa (16M) aliases
    //  [69,77M)  Kb  [S][1024] bf16 (8M)
    //  [77,85M)  Vt  [1024][S] bf16 (8M)
    char* ws = (char*)d_ws;
    unsigned short* Hb   = (unsigned short*)(ws);
    unsigned short* Qb   = (unsigned short*)(ws);
    unsigned short* Wqkv = (unsigned short*)(ws + (size_t)(18 << 20));
    unsigned short* QKVf = (unsigned short*)(ws + (size_t)(37 << 20));
    unsigned short* Oa   = (unsigned short*)(ws + (size_t)(37 << 20));
    unsigned short* Kb   = (unsigned short*)(ws + (size_t)(69 << 20));
    unsigned short* Vt   = (unsigned short*)(ws + (size_t)(77 << 20));

    cvt_bf16<<<(S * HID) / 1024, 256, 0, stream>>>(hidden, Hb);
    cvt_bf16<<<(QDIM * HID) / 1024, 256, 0, stream>>>(Wq, Wqkv);
    cvt_bf16<<<(KVDIM * HID) / 1024, 256, 0, stream>>>(Wk, Wqkv + (size_t)QDIM * HID);
    cvt_bf16<<<(KVDIM * HID) / 1024, 256, 0, stream>>>(Wv, Wqkv + (size_t)(QDIM + KVDIM) * HID);

    // fused QKV projection on the 256^2 8-phase kernel: grid 16x16 = 256 blocks
    bf16_gemm_8ph<<<256, 512, 0, stream>>>(Hb, Wqkv, QKVf, S, QKVDIM, HID);

    rope_kernel<<<(S * 12 * 128) / 256, 256, 0, stream>>>(QKVf, Qb, Kb, pos);
    transpose_v<<<dim3(S / 64, KVDIM / 64), 256, 0, stream>>>(QKVf, Vt);

    attn_kernel<<<512, 256, 0, stream>>>(Qb, Kb, Vt, Oa);

    cvt_bf16<<<(HID * QDIM) / 1024, 256, 0, stream>>>(Wo, Wqkv);
    bf16_gemm_bt<float><<<dim3(HID / 128, S / 128), 256, 0, stream>>>(Oa, Wqkv, out, S, HID, QDIM);
}

// Round 10
// 496.226 us; speedup vs baseline: 1.6137x; 1.1157x over previous
//
#include <hip/hip_runtime.h>
#include <hip/hip_bf16.h>
#include <math.h>

#define S 4096
#define HQ 8
#define NKVH 4
#define D 256
#define HID 2304
#define SW 2048
#define QDIM 2048
#define KVDIM 1024
#define QKVDIM 4096          // fused Q(2048) | K(1024) | V(1024)
#define SCALE 0.0625f
#define SOFTCAP 50.0f

typedef __attribute__((ext_vector_type(4))) float f32x4;
typedef __attribute__((ext_vector_type(8))) short short8;   // 8 bf16 = 4 VGPRs (MFMA A/B frag)

__device__ __forceinline__ float bf2f(unsigned v) { return __uint_as_float(v << 16); }
__device__ __forceinline__ unsigned f2bf(float f) {
    unsigned u = __float_as_uint(f);
    return (u + 0x7fffu + ((u >> 16) & 1u)) >> 16;   // round-to-nearest-even
}

__device__ __forceinline__ void store_c(float* p, float v) { *p = v; }
__device__ __forceinline__ void store_c(unsigned short* p, float v) { *p = (unsigned short)f2bf(v); }

// async global->LDS, 16B per lane; lds dst is wave-uniform base (HW adds lane*16)
__device__ __forceinline__ void glls16(const void* g, void* l) {
    __builtin_amdgcn_global_load_lds(
        (const __attribute__((address_space(1))) unsigned int*)g,
        (__attribute__((address_space(3))) unsigned int*)l, 16, 0, 0);
}

// ---------------------------------------------------------------------------
// fp32 -> bf16 elementwise (float4 per thread)
// ---------------------------------------------------------------------------
__global__ __launch_bounds__(256) void cvt_bf16(const float* __restrict__ in,
                                                unsigned short* __restrict__ out)
{
    int i = blockIdx.x * 256 + threadIdx.x;
    float4 v = ((const float4*)in)[i];
    uint2 o;
    o.x = f2bf(v.x) | (f2bf(v.y) << 16);
    o.y = f2bf(v.z) | (f2bf(v.w) << 16);
    ((uint2*)out)[i] = o;
}

// ---------------------------------------------------------------------------
// 256x256-tile 8-phase GEMM (T3+T4: counted vmcnt), bf16 in, TC out.
// 512 threads = 8 waves (2m x 4n), per-wave output 128x64, BK=64,
// 2 K-tiles/iteration. Fragment-major LDS (frag = 16 rows x 32 k = 1 KiB,
// staged linearly via global_load_lds, read as contiguous per-wave
// ds_read_b128) => conflict-free. LDS = 128 KiB, 1 block/CU.
//
// R10: REGISTER-CACHED OPERANDS. Quadrant phases share frag sets pairwise
// (A-mh0: ph1+ph2, A-mh1: ph3+ph4, B-nh0: ph1+ph3, B-nh1: ph2+ph4), so each
// set is ds_read ONCE per buffer: ph1 reads A-mh0+B-nh0, ph2 reads B-nh1,
// ph3 reads A-mh1, ph4 reads nothing. 24 ds_read_b128/K-tile/wave (was 48)
// -> LDS amplification 6x -> 3x. Stage/vmcnt/barrier schedule is byte-
// identical to the R6-verified ledger:
//   ph1: b1.A-mh1(t2I+1)  ph2: b1.B-nh1(t2I+1)
//   ph3: b0.A-mh0(t2I+2)  ph4: b0.B-nh0(t2I+2) + vmcnt(4)
//   ph5: b0.A-mh1(t2I+2)  ph6: b0.B-nh1(t2I+2)
//   ph7: b1.A-mh0(t2I+3)  ph8: b1.B-nh0(t2I+3) + vmcnt(4)
// Cached-read validity: every cached set is read inside its staged+synced
// window (vmcnt(4) ledger) and survives later LDS overwrites in registers.
// Grid: 1D nwg = (M/256)*(N/256) tiles, nwg % 8 == 0; nbn = N/256.
// ---------------------------------------------------------------------------
template <typename TC>
__global__ __launch_bounds__(512, 2) void bf16_gemm_8ph(const unsigned short* __restrict__ A,
                                                        const unsigned short* __restrict__ B,
                                                        TC* __restrict__ C,
                                                        int M, int N, int K, int nbn)
{
    __shared__ unsigned short As[2][32 * 512];   // 32 frags (16 m x 2 ks) x 1 KiB
    __shared__ unsigned short Bs[2][32 * 512];   // 32 frags (16 n x 2 ks) x 1 KiB
    const int t = threadIdx.x;
    const int w = t >> 6, lid = t & 63, n16 = lid & 15, quad = lid >> 4;

    // bijective XCD chunk swizzle (nwg % 8 == 0)
    const int nwg = gridDim.x;
    const int flat = blockIdx.x;
    const int wg = (flat & 7) * (nwg >> 3) + (flat >> 3);
    const int m0 = (wg / nbn) * 256, n0 = (wg % nbn) * 256;

    const int wmf = (w >> 2) * 8;             // wave m-frag base (0 or 8)
    const int wnf = (w & 3) * 4;              // wave n-frag base (0,4,8,12)
    const int fnw = (w >> 1) * 4 + (w & 1);   // B nh0 staging frag for this wave

    f32x4 acc[8][4] = {};
    short8 afr[4][2];        // cached A frags (current mh half)
    short8 bfr0[2][2];       // cached B frags, nh0 (used ph1+ph3 of a buffer)
    short8 bfr1[2][2];       // cached B frags, nh1 (used ph2+ph4)

    auto stageA = [&](int buf, int k0, int fm) {
        glls16(A + (size_t)(m0 + fm * 16 + n16) * K + k0 + quad * 8,
               &As[buf][(fm * 2 + 0) * 512]);
        glls16(A + (size_t)(m0 + fm * 16 + n16) * K + k0 + 32 + quad * 8,
               &As[buf][(fm * 2 + 1) * 512]);
    };
    auto stageB = [&](int buf, int k0, int fn) {
        glls16(B + (size_t)(n0 + fn * 16 + n16) * K + k0 + quad * 8,
               &Bs[buf][(fn * 2 + 0) * 512]);
        glls16(B + (size_t)(n0 + fn * 16 + n16) * K + k0 + 32 + quad * 8,
               &Bs[buf][(fn * 2 + 1) * 512]);
    };
    // bijective wave->frag assignments matching the read sets:
    auto sAm0 = [&](int buf, int k0){ stageA(buf, k0, (w & 3) + (w >> 2) * 8); };      // {0..3, 8..11}
    auto sAm1 = [&](int buf, int k0){ stageA(buf, k0, 4 + (w & 3) + (w >> 2) * 8); };  // {4..7, 12..15}
    auto sBn0 = [&](int buf, int k0){ stageB(buf, k0, fnw); };                          // {0,1,4,5,8,9,12,13}
    auto sBn1 = [&](int buf, int k0){ stageB(buf, k0, fnw + 2); };                      // {2,3,6,7,10,11,14,15}

// in-phase operand reads (issued after previous phase's closing barrier,
// waited by this phase's post-barrier lgkmcnt(0))
#define RD_A(mh, buf)                                                                \
    _Pragma("unroll") for (int i = 0; i < 4; ++i)                                    \
        _Pragma("unroll") for (int ks = 0; ks < 2; ++ks)                             \
            afr[i][ks] = *(const short8*)(&As[buf][((wmf + (mh)*4 + i)*2 + ks)*512 + lid*8]);
#define RD_B(dst, nh, buf)                                                           \
    _Pragma("unroll") for (int j = 0; j < 2; ++j)                                    \
        _Pragma("unroll") for (int ks = 0; ks < 2; ++ks)                             \
            dst[j][ks] = *(const short8*)(&Bs[buf][((wnf + (nh)*2 + j)*2 + ks)*512 + lid*8]);

#define GPHASE(mh, nh, BFR, STAGE, WAITSTR)                                          \
    {                                                                                \
        STAGE;                                                                       \
        __builtin_amdgcn_s_barrier();                                                \
        asm volatile("s_waitcnt lgkmcnt(0)" ::: "memory");                           \
        __builtin_amdgcn_sched_barrier(0);                                           \
        __builtin_amdgcn_s_setprio(1);                                               \
        _Pragma("unroll") for (int i = 0; i < 4; ++i)                                \
            _Pragma("unroll") for (int j = 0; j < 2; ++j)                            \
                _Pragma("unroll") for (int ks = 0; ks < 2; ++ks)                     \
                    acc[(mh)*4 + i][(nh)*2 + j] = __builtin_amdgcn_mfma_f32_16x16x32_bf16( \
                        afr[i][ks], BFR[j][ks], acc[(mh)*4 + i][(nh)*2 + j], 0, 0, 0); \
        __builtin_amdgcn_s_setprio(0);                                               \
        asm volatile(WAITSTR ::: "memory");                                          \
        __builtin_amdgcn_s_barrier();                                                \
    }

    const int nk = K / 64;
    const int niter = nk / 2;         // even nk required (2304/64=36 -> 18; 2048/64=32 -> 16)

    // prologue: all of b0 (tile 0), then b1.A-mh0 + b1.B-nh0 (tile 1)
    sAm0(0, 0); sBn0(0, 0); sAm1(0, 0); sBn1(0, 0);
    sAm0(1, 64); sBn0(1, 64);
    asm volatile("s_waitcnt vmcnt(4)" ::: "memory");   // first 8 glls (= all b0) done
    __builtin_amdgcn_s_barrier();

    for (int I = 0; I < niter - 1; ++I) {
        const int kc = I * 128;       // tile 2I at kc (b0), 2I+1 at kc+64 (b1)
        RD_A(0, 0) RD_B(bfr0, 0, 0)
        GPHASE(0, 0, bfr0, sAm1(1, kc + 64);,  "")
        RD_B(bfr1, 1, 0)
        GPHASE(0, 1, bfr1, sBn1(1, kc + 64);,  "")
        RD_A(1, 0)
        GPHASE(1, 0, bfr0, sAm0(0, kc + 128);, "")
        GPHASE(1, 1, bfr1, sBn0(0, kc + 128);, "s_waitcnt vmcnt(4)")
        RD_A(0, 1) RD_B(bfr0, 0, 1)
        GPHASE(0, 0, bfr0, sAm1(0, kc + 128);, "")
        RD_B(bfr1, 1, 1)
        GPHASE(0, 1, bfr1, sBn1(0, kc + 128);, "")
        RD_A(1, 1)
        GPHASE(1, 0, bfr0, sAm0(1, kc + 192);, "")
        GPHASE(1, 1, bfr1, sBn0(1, kc + 192);, "s_waitcnt vmcnt(4)")
    }
    // peeled last iteration: finish b1 (tile nk-1) in ph1/ph2, drain at ph4
    {
        const int kc = (niter - 1) * 128;
        RD_A(0, 0) RD_B(bfr0, 0, 0)
        GPHASE(0, 0, bfr0, sAm1(1, kc + 64);, "")
        RD_B(bfr1, 1, 0)
        GPHASE(0, 1, bfr1, sBn1(1, kc + 64);, "")
        RD_A(1, 0)
        GPHASE(1, 0, bfr0, {};,               "")
        GPHASE(1, 1, bfr1, {};,               "s_waitcnt vmcnt(0)")
        RD_A(0, 1) RD_B(bfr0, 0, 1)
        GPHASE(0, 0, bfr0, {};,               "")
        RD_B(bfr1, 1, 1)
        GPHASE(0, 1, bfr1, {};,               "")
        RD_A(1, 1)
        GPHASE(1, 0, bfr0, {};,               "")
        GPHASE(1, 1, bfr1, {};,               "")
    }
#undef GPHASE
#undef RD_A
#undef RD_B

    // C-write: rows m0 + (w>>2)*128 + mi*16 + quad*4 + rg; cols n0 + (w&3)*64 + nj*16 + n16
    #pragma unroll
    for (int mi = 0; mi < 8; ++mi) {
        #pragma unroll
        for (int nj = 0; nj < 4; ++nj) {
            int rbase = m0 + (w >> 2) * 128 + mi * 16 + quad * 4;
            int col   = n0 + (w & 3) * 64 + nj * 16 + n16;
            #pragma unroll
            for (int rg = 0; rg < 4; ++rg)
                store_c(C + (size_t)(rbase + rg) * N + col, acc[mi][nj][rg]);
        }
    }
}

// ---------------------------------------------------------------------------
// RoPE: read bf16 Q/K from fused QKV [S][4096], write Qb/Kb (SCALE folded).
// ---------------------------------------------------------------------------
__global__ __launch_bounds__(256) void rope_kernel(const unsigned short* __restrict__ QKV,
                                                   unsigned short* __restrict__ Qb,
                                                   unsigned short* __restrict__ Kb,
                                                   const int* __restrict__ pos_ids)
{
    int id   = blockIdx.x * 256 + threadIdx.x;   // S * 12 * 128 threads
    int d    = id & 127;
    int rest = id >> 7;
    int hh   = rest % 12;
    int i    = rest / 12;
    float pos = (float)pos_ids[i];
    float inv = __expf((float)d * (-9.210340371976184f / 128.0f));   // 10000^(-d/128)
    float ang = pos * inv;
    float sn, cs;
    sincosf(ang, &sn, &cs);
    if (hh < HQ) {
        const unsigned short* p = QKV + (size_t)i * QKVDIM + hh * D + d;
        float x0 = bf2f(p[0]), x1 = bf2f(p[128]);
        unsigned short* q = Qb + (size_t)i * QDIM + hh * D + d;
        q[0]   = (unsigned short)f2bf((x0 * cs - x1 * sn) * SCALE);
        q[128] = (unsigned short)f2bf((x1 * cs + x0 * sn) * SCALE);
    } else {
        const unsigned short* p = QKV + (size_t)i * QKVDIM + QDIM + (hh - HQ) * D + d;
        float x0 = bf2f(p[0]), x1 = bf2f(p[128]);
        unsigned short* k = Kb + (size_t)i * KVDIM + (hh - HQ) * D + d;
        k[0]   = (unsigned short)f2bf(x0 * cs - x1 * sn);
        k[128] = (unsigned short)f2bf(x1 * cs + x0 * sn);
    }
}

// ---------------------------------------------------------------------------
// V transpose: fused QKV [S][4096] cols 3072..4095 -> Vt [KVDIM][S] bf16.
// ---------------------------------------------------------------------------
__global__ __launch_bounds__(256) void transpose_v(const unsigned short* __restrict__ QKV,
                                                   unsigned short* __restrict__ Vt)
{
    __shared__ float tile[64][65];
    const int s0 = blockIdx.x * 64, d0 = blockIdx.y * 64;
    const int t = threadIdx.x;
    #pragma unroll
    for (int it = 0; it < 4; ++it) {
        int flat = it * 256 + t;
        int r  = flat >> 4;
        int c4 = (flat & 15) * 4;
        uint2 v = *(const uint2*)(QKV + (size_t)(s0 + r) * QKVDIM + (QDIM + KVDIM) + d0 + c4);
        tile[r][c4 + 0] = bf2f(v.x & 0xffffu); tile[r][c4 + 1] = bf2f(v.x >> 16);
        tile[r][c4 + 2] = bf2f(v.y & 0xffffu); tile[r][c4 + 3] = bf2f(v.y >> 16);
    }
    __syncthreads();
    #pragma unroll
    for (int it = 0; it < 4; ++it) {
        int flat = it * 256 + t;
        int dr  = flat >> 4;
        int sc4 = (flat & 15) * 4;
        uint2 o;
        o.x = f2bf(tile[sc4 + 0][dr]) | (f2bf(tile[sc4 + 1][dr]) << 16);
        o.y = f2bf(tile[sc4 + 2][dr]) | (f2bf(tile[sc4 + 3][dr]) << 16);
        *(uint2*)(Vt + (size_t)(d0 + dr) * S + s0 + sc4) = o;
    }
}

// ---------------------------------------------------------------------------
// MFMA flash attention: FIXED-MAX softmax + 64-key tiles + single-buffered
// LDS with T14 async-STAGE split, staging in 16 NAMED uint4 registers
// (rule-#20: no arrays/lambdas => VGPR residency; R9-verified, spill-free).
// Per iteration: vmcnt(0) -> commit regs->LDS -> barrier A -> issue next-tile
// loads (hide under compute) -> QK^T -> softmax/P -> PV -> barrier B.
// LDS = K 32K + V 32K + P 8K = 72K => 2 blocks/CU.
// ---------------------------------------------------------------------------
__global__ __launch_bounds__(256, 2) void attn_kernel(const unsigned short* __restrict__ Qb,
                                                      const unsigned short* __restrict__ Kb,
                                                      const unsigned short* __restrict__ Vt,
                                                      unsigned short* __restrict__ O)
{
    __shared__ unsigned short Ks[32 * 512];   // frag f=nt*8+ks: K[key=nt*16+n16][k=ks*32+quad*8]
    __shared__ unsigned short Vs[32 * 512];   // frag f=dt*2+ks2: Vt[d=dt*16+n16][key=ks2*32+quad*8]
    __shared__ unsigned short Ps[4 * 1024];   // per-wave 2 frags: P[16 rows][64 keys]
    const int t = threadIdx.x;
    const int bid = blockIdx.x;
    const int b2 = bid & 255;
    const int h = b2 & 7, kvh = h >> 1;
    const int u = b2 >> 3;
    const int g = (bid < 256) ? u : 63 - u;
    const int i0 = g * 64;
    const int w = t >> 6, lid = t & 63, n16 = lid & 15, quad = lid >> 4;
    const int qbase = i0 + w * 16;
    unsigned short* Pw = Ps + w * 1024;

    // per-wave K/V base addresses (frag f = it*4 + w)
    const unsigned short* Kbase = Kb + kvh * D + quad * 8;
    const unsigned short* Vbase = Vt + (size_t)(kvh * D + n16) * S + quad * 8;

    uint4 kr0, kr1, kr2, kr3, kr4, kr5, kr6, kr7;
    uint4 vr0, vr1, vr2, vr3, vr4, vr5, vr6, vr7;

// f = IT*4+w; K frag: nt=f>>3, ks=f&7 -> row j0+nt*16+n16, col ks*32
#define KADDR(J0, IT) (Kbase + (size_t)((J0) + (((IT)*4 + w) >> 3) * 16 + n16) * KVDIM + (((IT)*4 + w) & 7) * 32)
// V frag: dt=f>>1, ks2=f&1 -> row dt*16+n16 (folded in Vbase), col j0+ks2*32
#define VADDR(J0, IT) (Vbase + (size_t)((((IT)*4 + w) >> 1) * 16) * S + (J0) + (((IT)*4 + w) & 1) * 32)
#define ISSUE(J0) do { const int _j = (J0);                                   \
        kr0 = *(const uint4*)KADDR(_j, 0); kr1 = *(const uint4*)KADDR(_j, 1); \
        kr2 = *(const uint4*)KADDR(_j, 2); kr3 = *(const uint4*)KADDR(_j, 3); \
        kr4 = *(const uint4*)KADDR(_j, 4); kr5 = *(const uint4*)KADDR(_j, 5); \
        kr6 = *(const uint4*)KADDR(_j, 6); kr7 = *(const uint4*)KADDR(_j, 7); \
        vr0 = *(const uint4*)VADDR(_j, 0); vr1 = *(const uint4*)VADDR(_j, 1); \
        vr2 = *(const uint4*)VADDR(_j, 2); vr3 = *(const uint4*)VADDR(_j, 3); \
        vr4 = *(const uint4*)VADDR(_j, 4); vr5 = *(const uint4*)VADDR(_j, 5); \
        vr6 = *(const uint4*)VADDR(_j, 6); vr7 = *(const uint4*)VADDR(_j, 7); \
    } while (0)
#define COMMIT() do {                                                          \
        *(uint4*)(&Ks[(0*4 + w) * 512 + lid * 8]) = kr0;                       \
        *(uint4*)(&Ks[(1*4 + w) * 512 + lid * 8]) = kr1;                       \
        *(uint4*)(&Ks[(2*4 + w) * 512 + lid * 8]) = kr2;                       \
        *(uint4*)(&Ks[(3*4 + w) * 512 + lid * 8]) = kr3;                       \
        *(uint4*)(&Ks[(4*4 + w) * 512 + lid * 8]) = kr4;                       \
        *(uint4*)(&Ks[(5*4 + w) * 512 + lid * 8]) = kr5;                       \
        *(uint4*)(&Ks[(6*4 + w) * 512 + lid * 8]) = kr6;                       \
        *(uint4*)(&Ks[(7*4 + w) * 512 + lid * 8]) = kr7;                       \
        *(uint4*)(&Vs[(0*4 + w) * 512 + lid * 8]) = vr0;                       \
        *(uint4*)(&Vs[(1*4 + w) * 512 + lid * 8]) = vr1;                       \
        *(uint4*)(&Vs[(2*4 + w) * 512 + lid * 8]) = vr2;                       \
        *(uint4*)(&Vs[(3*4 + w) * 512 + lid * 8]) = vr3;                       \
        *(uint4*)(&Vs[(4*4 + w) * 512 + lid * 8]) = vr4;                       \
        *(uint4*)(&Vs[(5*4 + w) * 512 + lid * 8]) = vr5;                       \
        *(uint4*)(&Vs[(6*4 + w) * 512 + lid * 8]) = vr6;                       \
        *(uint4*)(&Vs[(7*4 + w) * 512 + lid * 8]) = vr7;                       \
    } while (0)

    // Q A-frags in registers: qf[ks], 16 rows per wave
    short8 qf[8];
    #pragma unroll
    for (int ks = 0; ks < 8; ++ks)
        qf[ks] = *(const short8*)(Qb + (size_t)(qbase + n16) * QDIM + h * D + ks * 32 + quad * 8);

    float lacc[4] = {0.f, 0.f, 0.f, 0.f};
    f32x4 Oacc[16] = {};

    const int jt_min = (i0 >= SW) ? ((i0 - (SW - 1)) >> 6) : 0;
    const int jt_max = (i0 + 63) >> 6;

    ISSUE(jt_min * 64);

    for (int jt = jt_min; jt <= jt_max; ++jt) {
        const int j0 = jt * 64;
        asm volatile("s_waitcnt vmcnt(0)" ::: "memory");   // own tile-j loads in regs
        COMMIT();                                          // regs -> LDS
        __syncthreads();                                   // barrier A: tile j visible
        if (jt < jt_max) ISSUE((jt + 1) * 64);             // next-tile loads under compute

        // ---- S = Q K^T (32 MFMA)
        f32x4 sc[4] = {};
        __builtin_amdgcn_s_setprio(1);
        #pragma unroll
        for (int ks = 0; ks < 8; ++ks) {
            #pragma unroll
            for (int nt = 0; nt < 4; ++nt) {
                short8 kf = *(const short8*)(&Ks[(nt * 8 + ks) * 512 + lid * 8]);
                sc[nt] = __builtin_amdgcn_mfma_f32_16x16x32_bf16(qf[ks], kf, sc[nt], 0, 0, 0);
            }
        }
        __builtin_amdgcn_s_setprio(0);

        // ---- fused softcap + fixed-max softmax: p = exp(-100/(exp(2s/50)+1))
        #pragma unroll
        for (int nt = 0; nt < 4; ++nt) {
            int j = j0 + nt * 16 + n16;
            #pragma unroll
            for (int rg = 0; rg < 4; ++rg) {
                int iq = qbase + quad * 4 + rg;
                float e = __expf(sc[nt][rg] * (2.0f / SOFTCAP));
                float p = __expf(-100.0f * __builtin_amdgcn_rcpf(e + 1.0f));
                bool ok = (j <= iq) && (iq - j < SW);
                p = ok ? p : 0.0f;
                lacc[rg] += p;
                // A-frag (32-key half ks2=nt>>1): lane' = row + 16*((nt&1)*2 + (n16>>3)), elem = n16&7
                Pw[(nt >> 1) * 512 + (quad * 4 + rg + 16 * ((nt & 1) * 2 + (n16 >> 3))) * 8 + (n16 & 7)]
                    = (unsigned short)f2bf(p);
            }
        }

        asm volatile("s_waitcnt lgkmcnt(0)" ::: "memory");   // P writes visible (wave-private)

        // ---- O += P V (32 MFMA)
        short8 pf0 = *(const short8*)(Pw + lid * 8);
        short8 pf1 = *(const short8*)(Pw + 512 + lid * 8);
        __builtin_amdgcn_s_setprio(1);
        #pragma unroll
        for (int dt = 0; dt < 16; ++dt) {
            short8 vf0 = *(const short8*)(&Vs[(dt * 2 + 0) * 512 + lid * 8]);
            Oacc[dt] = __builtin_amdgcn_mfma_f32_16x16x32_bf16(pf0, vf0, Oacc[dt], 0, 0, 0);
            short8 vf1 = *(const short8*)(&Vs[(dt * 2 + 1) * 512 + lid * 8]);
            Oacc[dt] = __builtin_amdgcn_mfma_f32_16x16x32_bf16(pf1, vf1, Oacc[dt], 0, 0, 0);
        }
        __builtin_amdgcn_s_setprio(0);

        __syncthreads();                                   // barrier B: reads of tile j done
    }
#undef KADDR
#undef VADDR
#undef ISSUE
#undef COMMIT

    // final row-sum reduce across the 16 key-lanes (once)
    float linv[4];
    #pragma unroll
    for (int rg = 0; rg < 4; ++rg) {
        float rs = lacc[rg];
        rs += __shfl_xor(rs, 1); rs += __shfl_xor(rs, 2);
        rs += __shfl_xor(rs, 4); rs += __shfl_xor(rs, 8);
        linv[rg] = 1.0f / rs;
    }
    #pragma unroll
    for (int dt = 0; dt < 16; ++dt) {
        int col = h * D + dt * 16 + n16;
        #pragma unroll
        for (int rg = 0; rg < 4; ++rg) {
            int row = qbase + quad * 4 + rg;
            O[(size_t)row * QDIM + col] = (unsigned short)f2bf(Oacc[dt][rg] * linv[rg]);
        }
    }
}

extern "C" void kernel_launch(void* const* d_in, const int* in_sizes, int n_in,
                              void* d_out, int out_size, void* d_ws, size_t ws_size,
                              hipStream_t stream) {
    const float* hidden = (const float*)d_in[0];
    // d_in[1] = attention_mask: recomputed analytically, not read
    const float* Wq = (const float*)d_in[2];
    const float* Wk = (const float*)d_in[3];
    const float* Wv = (const float*)d_in[4];
    const float* Wo = (const float*)d_in[5];
    const int* pos = (const int*)d_in[6];
    float* out = (float*)d_out;

    // workspace layout (85 MiB total, aggressive aliasing):
    //  [0,18M)   Hb  [S][2304] bf16            -> dead after QKV GEMM; Qb [S][2048] aliases
    //  [18,37M)  Wqkv bf16 (19M)               -> dead after QKV GEMM; Wo bf16 (9M) aliases
    //  [37,69M)  QKVf [S][4096] bf16 (32M)     -> dead after rope+transpose; Oa (16M) aliases
    //  [69,77M)  Kb  [S][1024] bf16 (8M)
    //  [77,85M)  Vt  [1024][S] bf16 (8M)
    char* ws = (char*)d_ws;
    unsigned short* Hb   = (unsigned short*)(ws);
    unsigned short* Qb   = (unsigned short*)(ws);
    unsigned short* Wqkv = (unsigned short*)(ws + (size_t)(18 << 20));
    unsigned short* QKVf = (unsigned short*)(ws + (size_t)(37 << 20));
    unsigned short* Oa   = (unsigned short*)(ws + (size_t)(37 << 20));
    unsigned short* Kb   = (unsigned short*)(ws + (size_t)(69 << 20));
    unsigned short* Vt   = (unsigned short*)(ws + (size_t)(77 << 20));

    cvt_bf16<<<(S * HID) / 1024, 256, 0, stream>>>(hidden, Hb);
    cvt_bf16<<<(QDIM * HID) / 1024, 256, 0, stream>>>(Wq, Wqkv);
    cvt_bf16<<<(KVDIM * HID) / 1024, 256, 0, stream>>>(Wk, Wqkv + (size_t)QDIM * HID);
    cvt_bf16<<<(KVDIM * HID) / 1024, 256, 0, stream>>>(Wv, Wqkv + (size_t)(QDIM + KVDIM) * HID);

    // fused QKV projection: [4096][2304] @ [4096][2304]^T -> [4096][4096]
    // grid = (4096/256)*(4096/256) = 256 tiles, nbn = 16
    bf16_gemm_8ph<unsigned short><<<256, 512, 0, stream>>>(Hb, Wqkv, QKVf, S, QKVDIM, HID, 16);

    rope_kernel<<<(S * 12 * 128) / 256, 256, 0, stream>>>(QKVf, Qb, Kb, pos);
    transpose_v<<<dim3(S / 64, KVDIM / 64), 256, 0, stream>>>(QKVf, Vt);

    attn_kernel<<<512, 256, 0, stream>>>(Qb, Kb, Vt, Oa);

    cvt_bf16<<<(HID * QDIM) / 1024, 256, 0, stream>>>(Wo, Wqkv);
    // O-projection on the same 8-phase kernel: grid = 16 * (2304/256=9) = 144, nbn = 9
    bf16_gemm_8ph<float><<<144, 512, 0, stream>>>(Oa, Wqkv, out, S, HID, QDIM, 9);
}

// Round 11
// 488.575 us; speedup vs baseline: 1.6390x; 1.0157x over previous
//
#include <hip/hip_runtime.h>
#include <hip/hip_bf16.h>
#include <math.h>

#define S 4096
#define HQ 8
#define NKVH 4
#define D 256
#define HID 2304
#define SW 2048
#define QDIM 2048
#define KVDIM 1024
#define QKVDIM 4096          // fused Q(2048) | K(1024) | V(1024)
#define SCALE 0.0625f
#define SOFTCAP 50.0f

typedef __attribute__((ext_vector_type(4))) float f32x4;
typedef __attribute__((ext_vector_type(8))) short short8;   // 8 bf16 = 4 VGPRs (MFMA A/B frag)
typedef __attribute__((ext_vector_type(8))) unsigned short ushort8;

__device__ __forceinline__ float bf2f(unsigned v) { return __uint_as_float(v << 16); }
__device__ __forceinline__ unsigned f2bf(float f) {
    unsigned u = __float_as_uint(f);
    return (u + 0x7fffu + ((u >> 16) & 1u)) >> 16;   // round-to-nearest-even
}

__device__ __forceinline__ void store_c(float* p, float v) { *p = v; }
__device__ __forceinline__ void store_c(unsigned short* p, float v) { *p = (unsigned short)f2bf(v); }

// async global->LDS, 16B per lane; lds dst is wave-uniform base (HW adds lane*16)
__device__ __forceinline__ void glls16(const void* g, void* l) {
    __builtin_amdgcn_global_load_lds(
        (const __attribute__((address_space(1))) unsigned int*)g,
        (__attribute__((address_space(3))) unsigned int*)l, 16, 0, 0);
}

// ---------------------------------------------------------------------------
// fp32 -> bf16 elementwise (float4 per thread)
// ---------------------------------------------------------------------------
__global__ __launch_bounds__(256) void cvt_bf16(const float* __restrict__ in,
                                                unsigned short* __restrict__ out)
{
    int i = blockIdx.x * 256 + threadIdx.x;
    float4 v = ((const float4*)in)[i];
    uint2 o;
    o.x = f2bf(v.x) | (f2bf(v.y) << 16);
    o.y = f2bf(v.z) | (f2bf(v.w) << 16);
    ((uint2*)out)[i] = o;
}

// ---------------------------------------------------------------------------
// 256x256-tile 8-phase GEMM (T3+T4: counted vmcnt), bf16 in, TC out.
// 512 threads = 8 waves (2m x 4n), per-wave output 128x64, BK=64,
// 2 K-tiles/iteration. Fragment-major LDS => conflict-free. LDS = 128 KiB.
// R10: register-cached operands (24 ds_read_b128/K-tile/wave).
// R11: UNPINNED SCHEDULING — removed the per-phase lgkmcnt(0)+sched_barrier(0)
// (m141: order-pinning cost 874->510 TF on the m97 kernel; rule #18 only
// applies to inline-asm ds_reads — ours are compiler loads, so the compiler
// emits fine-grained lgkmcnt(4/3/1/0) interleaved with MFMAs on its own).
// Safety: staged-data visibility = vmcnt(4)+closing-barrier pairs (ledger
// unchanged); a zero-cost `asm("":::"memory")` after each closing barrier
// pins next-phase ds_reads below it (loads cannot cross a memory clobber).
// Ledger (verified R6):
//   ph1: b1.A-mh1(t2I+1)  ph2: b1.B-nh1(t2I+1)
//   ph3: b0.A-mh0(t2I+2)  ph4: b0.B-nh0(t2I+2) + vmcnt(4)
//   ph5: b0.A-mh1(t2I+2)  ph6: b0.B-nh1(t2I+2)
//   ph7: b1.A-mh0(t2I+3)  ph8: b1.B-nh0(t2I+3) + vmcnt(4)
// Grid: 1D nwg = (M/256)*(N/256) tiles, nwg % 8 == 0; nbn = N/256.
// ---------------------------------------------------------------------------
template <typename TC>
__global__ __launch_bounds__(512, 2) void bf16_gemm_8ph(const unsigned short* __restrict__ A,
                                                        const unsigned short* __restrict__ B,
                                                        TC* __restrict__ C,
                                                        int M, int N, int K, int nbn)
{
    __shared__ unsigned short As[2][32 * 512];   // 32 frags (16 m x 2 ks) x 1 KiB
    __shared__ unsigned short Bs[2][32 * 512];   // 32 frags (16 n x 2 ks) x 1 KiB
    const int t = threadIdx.x;
    const int w = t >> 6, lid = t & 63, n16 = lid & 15, quad = lid >> 4;

    // bijective XCD chunk swizzle (nwg % 8 == 0)
    const int nwg = gridDim.x;
    const int flat = blockIdx.x;
    const int wg = (flat & 7) * (nwg >> 3) + (flat >> 3);
    const int m0 = (wg / nbn) * 256, n0 = (wg % nbn) * 256;

    const int wmf = (w >> 2) * 8;             // wave m-frag base (0 or 8)
    const int wnf = (w & 3) * 4;              // wave n-frag base (0,4,8,12)
    const int fnw = (w >> 1) * 4 + (w & 1);   // B nh0 staging frag for this wave

    f32x4 acc[8][4] = {};
    short8 afr[4][2];        // cached A frags (current mh half)
    short8 bfr0[2][2];       // cached B frags, nh0 (used ph1+ph3 of a buffer)
    short8 bfr1[2][2];       // cached B frags, nh1 (used ph2+ph4)

    auto stageA = [&](int buf, int k0, int fm) {
        glls16(A + (size_t)(m0 + fm * 16 + n16) * K + k0 + quad * 8,
               &As[buf][(fm * 2 + 0) * 512]);
        glls16(A + (size_t)(m0 + fm * 16 + n16) * K + k0 + 32 + quad * 8,
               &As[buf][(fm * 2 + 1) * 512]);
    };
    auto stageB = [&](int buf, int k0, int fn) {
        glls16(B + (size_t)(n0 + fn * 16 + n16) * K + k0 + quad * 8,
               &Bs[buf][(fn * 2 + 0) * 512]);
        glls16(B + (size_t)(n0 + fn * 16 + n16) * K + k0 + 32 + quad * 8,
               &Bs[buf][(fn * 2 + 1) * 512]);
    };
    // bijective wave->frag assignments matching the read sets:
    auto sAm0 = [&](int buf, int k0){ stageA(buf, k0, (w & 3) + (w >> 2) * 8); };      // {0..3, 8..11}
    auto sAm1 = [&](int buf, int k0){ stageA(buf, k0, 4 + (w & 3) + (w >> 2) * 8); };  // {4..7, 12..15}
    auto sBn0 = [&](int buf, int k0){ stageB(buf, k0, fnw); };                          // {0,1,4,5,8,9,12,13}
    auto sBn1 = [&](int buf, int k0){ stageB(buf, k0, fnw + 2); };                      // {2,3,6,7,10,11,14,15}

// in-phase operand reads (issued after previous phase's closing barrier;
// compiler inserts fine-grained lgkmcnt before each consuming MFMA)
#define RD_A(mh, buf)                                                                \
    _Pragma("unroll") for (int i = 0; i < 4; ++i)                                    \
        _Pragma("unroll") for (int ks = 0; ks < 2; ++ks)                             \
            afr[i][ks] = *(const short8*)(&As[buf][((wmf + (mh)*4 + i)*2 + ks)*512 + lid*8]);
#define RD_B(dst, nh, buf)                                                           \
    _Pragma("unroll") for (int j = 0; j < 2; ++j)                                    \
        _Pragma("unroll") for (int ks = 0; ks < 2; ++ks)                             \
            dst[j][ks] = *(const short8*)(&Bs[buf][((wnf + (nh)*2 + j)*2 + ks)*512 + lid*8]);

#define GPHASE(mh, nh, BFR, STAGE, WAITSTR)                                          \
    {                                                                                \
        STAGE;                                                                       \
        __builtin_amdgcn_s_barrier();                                                \
        __builtin_amdgcn_s_setprio(1);                                               \
        _Pragma("unroll") for (int i = 0; i < 4; ++i)                                \
            _Pragma("unroll") for (int j = 0; j < 2; ++j)                            \
                _Pragma("unroll") for (int ks = 0; ks < 2; ++ks)                     \
                    acc[(mh)*4 + i][(nh)*2 + j] = __builtin_amdgcn_mfma_f32_16x16x32_bf16( \
                        afr[i][ks], BFR[j][ks], acc[(mh)*4 + i][(nh)*2 + j], 0, 0, 0); \
        __builtin_amdgcn_s_setprio(0);                                               \
        asm volatile(WAITSTR ::: "memory");                                          \
        __builtin_amdgcn_s_barrier();                                                \
        asm volatile("" ::: "memory");  /* pin following ds_reads below barrier */   \
    }

    const int nk = K / 64;
    const int niter = nk / 2;         // even nk required (2304/64=36 -> 18; 2048/64=32 -> 16)

    // prologue: all of b0 (tile 0), then b1.A-mh0 + b1.B-nh0 (tile 1)
    sAm0(0, 0); sBn0(0, 0); sAm1(0, 0); sBn1(0, 0);
    sAm0(1, 64); sBn0(1, 64);
    asm volatile("s_waitcnt vmcnt(4)" ::: "memory");   // first 8 glls (= all b0) done
    __builtin_amdgcn_s_barrier();
    asm volatile("" ::: "memory");

    for (int I = 0; I < niter - 1; ++I) {
        const int kc = I * 128;       // tile 2I at kc (b0), 2I+1 at kc+64 (b1)
        RD_A(0, 0) RD_B(bfr0, 0, 0)
        GPHASE(0, 0, bfr0, sAm1(1, kc + 64);,  "")
        RD_B(bfr1, 1, 0)
        GPHASE(0, 1, bfr1, sBn1(1, kc + 64);,  "")
        RD_A(1, 0)
        GPHASE(1, 0, bfr0, sAm0(0, kc + 128);, "")
        GPHASE(1, 1, bfr1, sBn0(0, kc + 128);, "s_waitcnt vmcnt(4)")
        RD_A(0, 1) RD_B(bfr0, 0, 1)
        GPHASE(0, 0, bfr0, sAm1(0, kc + 128);, "")
        RD_B(bfr1, 1, 1)
        GPHASE(0, 1, bfr1, sBn1(0, kc + 128);, "")
        RD_A(1, 1)
        GPHASE(1, 0, bfr0, sAm0(1, kc + 192);, "")
        GPHASE(1, 1, bfr1, sBn0(1, kc + 192);, "s_waitcnt vmcnt(4)")
    }
    // peeled last iteration: finish b1 (tile nk-1) in ph1/ph2, drain at ph4
    {
        const int kc = (niter - 1) * 128;
        RD_A(0, 0) RD_B(bfr0, 0, 0)
        GPHASE(0, 0, bfr0, sAm1(1, kc + 64);, "")
        RD_B(bfr1, 1, 0)
        GPHASE(0, 1, bfr1, sBn1(1, kc + 64);, "")
        RD_A(1, 0)
        GPHASE(1, 0, bfr0, {};,               "")
        GPHASE(1, 1, bfr1, {};,               "s_waitcnt vmcnt(0)")
        RD_A(0, 1) RD_B(bfr0, 0, 1)
        GPHASE(0, 0, bfr0, {};,               "")
        RD_B(bfr1, 1, 1)
        GPHASE(0, 1, bfr1, {};,               "")
        RD_A(1, 1)
        GPHASE(1, 0, bfr0, {};,               "")
        GPHASE(1, 1, bfr1, {};,               "")
    }
#undef GPHASE
#undef RD_A
#undef RD_B

    // C-write: rows m0 + (w>>2)*128 + mi*16 + quad*4 + rg; cols n0 + (w&3)*64 + nj*16 + n16
    #pragma unroll
    for (int mi = 0; mi < 8; ++mi) {
        #pragma unroll
        for (int nj = 0; nj < 4; ++nj) {
            int rbase = m0 + (w >> 2) * 128 + mi * 16 + quad * 4;
            int col   = n0 + (w & 3) * 64 + nj * 16 + n16;
            #pragma unroll
            for (int rg = 0; rg < 4; ++rg)
                store_c(C + (size_t)(rbase + rg) * N + col, acc[mi][nj][rg]);
        }
    }
}

// ---------------------------------------------------------------------------
// RoPE: read bf16 Q/K from fused QKV [S][4096], write Qb/Kb (SCALE folded).
// R11: vectorized x8 (ushort8 = 16B loads/stores) + native __sinf/__cosf
// (accurate sincosf's Payne-Hanek reduction dominated; 4e-4 rad error is
// 10x below bf16 ulp). Grid: S*12*16 threads.
// ---------------------------------------------------------------------------
__global__ __launch_bounds__(256) void rope_kernel(const unsigned short* __restrict__ QKV,
                                                   unsigned short* __restrict__ Qb,
                                                   unsigned short* __restrict__ Kb,
                                                   const int* __restrict__ pos_ids)
{
    int id   = blockIdx.x * 256 + threadIdx.x;   // S * 12 * 16 threads
    int d8   = (id & 15) * 8;                    // d base 0..120
    int rest = id >> 4;
    int hh   = rest % 12;
    int i    = rest / 12;
    float pos = (float)pos_ids[i];

    const unsigned short* p;
    unsigned short* o;
    float scale;
    if (hh < HQ) {
        p = QKV + (size_t)i * QKVDIM + hh * D + d8;
        o = Qb + (size_t)i * QDIM + hh * D + d8;
        scale = SCALE;
    } else {
        p = QKV + (size_t)i * QKVDIM + QDIM + (hh - HQ) * D + d8;
        o = Kb + (size_t)i * KVDIM + (hh - HQ) * D + d8;
        scale = 1.0f;
    }
    ushort8 a = *(const ushort8*)(p);
    ushort8 b = *(const ushort8*)(p + 128);
    ushort8 oa, ob;
    #pragma unroll
    for (int j = 0; j < 8; ++j) {
        float inv = __expf((float)(d8 + j) * (-9.210340371976184f / 128.0f));   // 10000^(-d/128)
        float ang = pos * inv;
        float sn = __sinf(ang), cs = __cosf(ang);
        float x0 = bf2f(a[j]), x1 = bf2f(b[j]);
        oa[j] = (unsigned short)f2bf((x0 * cs - x1 * sn) * scale);
        ob[j] = (unsigned short)f2bf((x1 * cs + x0 * sn) * scale);
    }
    *(ushort8*)(o) = oa;
    *(ushort8*)(o + 128) = ob;
}

// ---------------------------------------------------------------------------
// V transpose: fused QKV [S][4096] cols 3072..4095 -> Vt [KVDIM][S] bf16.
// ---------------------------------------------------------------------------
__global__ __launch_bounds__(256) void transpose_v(const unsigned short* __restrict__ QKV,
                                                   unsigned short* __restrict__ Vt)
{
    __shared__ float tile[64][65];
    const int s0 = blockIdx.x * 64, d0 = blockIdx.y * 64;
    const int t = threadIdx.x;
    #pragma unroll
    for (int it = 0; it < 4; ++it) {
        int flat = it * 256 + t;
        int r  = flat >> 4;
        int c4 = (flat & 15) * 4;
        uint2 v = *(const uint2*)(QKV + (size_t)(s0 + r) * QKVDIM + (QDIM + KVDIM) + d0 + c4);
        tile[r][c4 + 0] = bf2f(v.x & 0xffffu); tile[r][c4 + 1] = bf2f(v.x >> 16);
        tile[r][c4 + 2] = bf2f(v.y & 0xffffu); tile[r][c4 + 3] = bf2f(v.y >> 16);
    }
    __syncthreads();
    #pragma unroll
    for (int it = 0; it < 4; ++it) {
        int flat = it * 256 + t;
        int dr  = flat >> 4;
        int sc4 = (flat & 15) * 4;
        uint2 o;
        o.x = f2bf(tile[sc4 + 0][dr]) | (f2bf(tile[sc4 + 1][dr]) << 16);
        o.y = f2bf(tile[sc4 + 2][dr]) | (f2bf(tile[sc4 + 3][dr]) << 16);
        *(uint2*)(Vt + (size_t)(d0 + dr) * S + s0 + sc4) = o;
    }
}

// ---------------------------------------------------------------------------
// MFMA flash attention: FIXED-MAX softmax + 64-key tiles + single-buffered
// LDS with T14 async-STAGE split, staging in 16 NAMED uint4 registers
// (rule-#20: no arrays/lambdas => VGPR residency; R9-verified, spill-free).
// Per iteration: vmcnt(0) -> commit regs->LDS -> barrier A -> issue next-tile
// loads (hide under compute) -> QK^T -> softmax/P -> PV -> barrier B.
// LDS = K 32K + V 32K + P 8K = 72K => 2 blocks/CU.
// ---------------------------------------------------------------------------
__global__ __launch_bounds__(256, 2) void attn_kernel(const unsigned short* __restrict__ Qb,
                                                      const unsigned short* __restrict__ Kb,
                                                      const unsigned short* __restrict__ Vt,
                                                      unsigned short* __restrict__ O)
{
    __shared__ unsigned short Ks[32 * 512];   // frag f=nt*8+ks: K[key=nt*16+n16][k=ks*32+quad*8]
    __shared__ unsigned short Vs[32 * 512];   // frag f=dt*2+ks2: Vt[d=dt*16+n16][key=ks2*32+quad*8]
    __shared__ unsigned short Ps[4 * 1024];   // per-wave 2 frags: P[16 rows][64 keys]
    const int t = threadIdx.x;
    const int bid = blockIdx.x;
    const int b2 = bid & 255;
    const int h = b2 & 7, kvh = h >> 1;
    const int u = b2 >> 3;
    const int g = (bid < 256) ? u : 63 - u;
    const int i0 = g * 64;
    const int w = t >> 6, lid = t & 63, n16 = lid & 15, quad = lid >> 4;
    const int qbase = i0 + w * 16;
    unsigned short* Pw = Ps + w * 1024;

    // per-wave K/V base addresses (frag f = it*4 + w)
    const unsigned short* Kbase = Kb + kvh * D + quad * 8;
    const unsigned short* Vbase = Vt + (size_t)(kvh * D + n16) * S + quad * 8;

    uint4 kr0, kr1, kr2, kr3, kr4, kr5, kr6, kr7;
    uint4 vr0, vr1, vr2, vr3, vr4, vr5, vr6, vr7;

// f = IT*4+w; K frag: nt=f>>3, ks=f&7 -> row j0+nt*16+n16, col ks*32
#define KADDR(J0, IT) (Kbase + (size_t)((J0) + (((IT)*4 + w) >> 3) * 16 + n16) * KVDIM + (((IT)*4 + w) & 7) * 32)
// V frag: dt=f>>1, ks2=f&1 -> row dt*16+n16 (folded in Vbase), col j0+ks2*32
#define VADDR(J0, IT) (Vbase + (size_t)((((IT)*4 + w) >> 1) * 16) * S + (J0) + (((IT)*4 + w) & 1) * 32)
#define ISSUE(J0) do { const int _j = (J0);                                   \
        kr0 = *(const uint4*)KADDR(_j, 0); kr1 = *(const uint4*)KADDR(_j, 1); \
        kr2 = *(const uint4*)KADDR(_j, 2); kr3 = *(const uint4*)KADDR(_j, 3); \
        kr4 = *(const uint4*)KADDR(_j, 4); kr5 = *(const uint4*)KADDR(_j, 5); \
        kr6 = *(const uint4*)KADDR(_j, 6); kr7 = *(const uint4*)KADDR(_j, 7); \
        vr0 = *(const uint4*)VADDR(_j, 0); vr1 = *(const uint4*)VADDR(_j, 1); \
        vr2 = *(const uint4*)VADDR(_j, 2); vr3 = *(const uint4*)VADDR(_j, 3); \
        vr4 = *(const uint4*)VADDR(_j, 4); vr5 = *(const uint4*)VADDR(_j, 5); \
        vr6 = *(const uint4*)VADDR(_j, 6); vr7 = *(const uint4*)VADDR(_j, 7); \
    } while (0)
#define COMMIT() do {                                                          \
        *(uint4*)(&Ks[(0*4 + w) * 512 + lid * 8]) = kr0;                       \
        *(uint4*)(&Ks[(1*4 + w) * 512 + lid * 8]) = kr1;                       \
        *(uint4*)(&Ks[(2*4 + w) * 512 + lid * 8]) = kr2;                       \
        *(uint4*)(&Ks[(3*4 + w) * 512 + lid * 8]) = kr3;                       \
        *(uint4*)(&Ks[(4*4 + w) * 512 + lid * 8]) = kr4;                       \
        *(uint4*)(&Ks[(5*4 + w) * 512 + lid * 8]) = kr5;                       \
        *(uint4*)(&Ks[(6*4 + w) * 512 + lid * 8]) = kr6;                       \
        *(uint4*)(&Ks[(7*4 + w) * 512 + lid * 8]) = kr7;                       \
        *(uint4*)(&Vs[(0*4 + w) * 512 + lid * 8]) = vr0;                       \
        *(uint4*)(&Vs[(1*4 + w) * 512 + lid * 8]) = vr1;                       \
        *(uint4*)(&Vs[(2*4 + w) * 512 + lid * 8]) = vr2;                       \
        *(uint4*)(&Vs[(3*4 + w) * 512 + lid * 8]) = vr3;                       \
        *(uint4*)(&Vs[(4*4 + w) * 512 + lid * 8]) = vr4;                       \
        *(uint4*)(&Vs[(5*4 + w) * 512 + lid * 8]) = vr5;                       \
        *(uint4*)(&Vs[(6*4 + w) * 512 + lid * 8]) = vr6;                       \
        *(uint4*)(&Vs[(7*4 + w) * 512 + lid * 8]) = vr7;                       \
    } while (0)

    // Q A-frags in registers: qf[ks], 16 rows per wave
    short8 qf[8];
    #pragma unroll
    for (int ks = 0; ks < 8; ++ks)
        qf[ks] = *(const short8*)(Qb + (size_t)(qbase + n16) * QDIM + h * D + ks * 32 + quad * 8);

    float lacc[4] = {0.f, 0.f, 0.f, 0.f};
    f32x4 Oacc[16] = {};

    const int jt_min = (i0 >= SW) ? ((i0 - (SW - 1)) >> 6) : 0;
    const int jt_max = (i0 + 63) >> 6;

    ISSUE(jt_min * 64);

    for (int jt = jt_min; jt <= jt_max; ++jt) {
        const int j0 = jt * 64;
        asm volatile("s_waitcnt vmcnt(0)" ::: "memory");   // own tile-j loads in regs
        COMMIT();                                          // regs -> LDS
        __syncthreads();                                   // barrier A: tile j visible
        if (jt < jt_max) ISSUE((jt + 1) * 64);             // next-tile loads under compute

        // ---- S = Q K^T (32 MFMA)
        f32x4 sc[4] = {};
        __builtin_amdgcn_s_setprio(1);
        #pragma unroll
        for (int ks = 0; ks < 8; ++ks) {
            #pragma unroll
            for (int nt = 0; nt < 4; ++nt) {
                short8 kf = *(const short8*)(&Ks[(nt * 8 + ks) * 512 + lid * 8]);
                sc[nt] = __builtin_amdgcn_mfma_f32_16x16x32_bf16(qf[ks], kf, sc[nt], 0, 0, 0);
            }
        }
        __builtin_amdgcn_s_setprio(0);

        // ---- fused softcap + fixed-max softmax: p = exp(-100/(exp(2s/50)+1))
        #pragma unroll
        for (int nt = 0; nt < 4; ++nt) {
            int j = j0 + nt * 16 + n16;
            #pragma unroll
            for (int rg = 0; rg < 4; ++rg) {
                int iq = qbase + quad * 4 + rg;
                float e = __expf(sc[nt][rg] * (2.0f / SOFTCAP));
                float p = __expf(-100.0f * __builtin_amdgcn_rcpf(e + 1.0f));
                bool ok = (j <= iq) && (iq - j < SW);
                p = ok ? p : 0.0f;
                lacc[rg] += p;
                // A-frag (32-key half ks2=nt>>1): lane' = row + 16*((nt&1)*2 + (n16>>3)), elem = n16&7
                Pw[(nt >> 1) * 512 + (quad * 4 + rg + 16 * ((nt & 1) * 2 + (n16 >> 3))) * 8 + (n16 & 7)]
                    = (unsigned short)f2bf(p);
            }
        }

        asm volatile("s_waitcnt lgkmcnt(0)" ::: "memory");   // P writes visible (wave-private)

        // ---- O += P V (32 MFMA)
        short8 pf0 = *(const short8*)(Pw + lid * 8);
        short8 pf1 = *(const short8*)(Pw + 512 + lid * 8);
        __builtin_amdgcn_s_setprio(1);
        #pragma unroll
        for (int dt = 0; dt < 16; ++dt) {
            short8 vf0 = *(const short8*)(&Vs[(dt * 2 + 0) * 512 + lid * 8]);
            Oacc[dt] = __builtin_amdgcn_mfma_f32_16x16x32_bf16(pf0, vf0, Oacc[dt], 0, 0, 0);
            short8 vf1 = *(const short8*)(&Vs[(dt * 2 + 1) * 512 + lid * 8]);
            Oacc[dt] = __builtin_amdgcn_mfma_f32_16x16x32_bf16(pf1, vf1, Oacc[dt], 0, 0, 0);
        }
        __builtin_amdgcn_s_setprio(0);

        __syncthreads();                                   // barrier B: reads of tile j done
    }
#undef KADDR
#undef VADDR
#undef ISSUE
#undef COMMIT

    // final row-sum reduce across the 16 key-lanes (once)
    float linv[4];
    #pragma unroll
    for (int rg = 0; rg < 4; ++rg) {
        float rs = lacc[rg];
        rs += __shfl_xor(rs, 1); rs += __shfl_xor(rs, 2);
        rs += __shfl_xor(rs, 4); rs += __shfl_xor(rs, 8);
        linv[rg] = 1.0f / rs;
    }
    #pragma unroll
    for (int dt = 0; dt < 16; ++dt) {
        int col = h * D + dt * 16 + n16;
        #pragma unroll
        for (int rg = 0; rg < 4; ++rg) {
            int row = qbase + quad * 4 + rg;
            O[(size_t)row * QDIM + col] = (unsigned short)f2bf(Oacc[dt][rg] * linv[rg]);
        }
    }
}

extern "C" void kernel_launch(void* const* d_in, const int* in_sizes, int n_in,
                              void* d_out, int out_size, void* d_ws, size_t ws_size,
                              hipStream_t stream) {
    const float* hidden = (const float*)d_in[0];
    // d_in[1] = attention_mask: recomputed analytically, not read
    const float* Wq = (const float*)d_in[2];
    const float* Wk = (const float*)d_in[3];
    const float* Wv = (const float*)d_in[4];
    const float* Wo = (const float*)d_in[5];
    const int* pos = (const int*)d_in[6];
    float* out = (float*)d_out;

    // workspace layout (85 MiB total, aggressive aliasing):
    //  [0,18M)   Hb  [S][2304] bf16            -> dead after QKV GEMM; Qb [S][2048] aliases
    //  [18,37M)  Wqkv bf16 (19M)               -> dead after QKV GEMM; Wo bf16 (9M) aliases
    //  [37,69M)  QKVf [S][4096] bf16 (32M)     -> dead after rope+transpose; Oa (16M) aliases
    //  [69,77M)  Kb  [S][1024] bf16 (8M)
    //  [77,85M)  Vt  [1024][S] bf16 (8M)
    char* ws = (char*)d_ws;
    unsigned short* Hb   = (unsigned short*)(ws);
    unsigned short* Qb   = (unsigned short*)(ws);
    unsigned short* Wqkv = (unsigned short*)(ws + (size_t)(18 << 20));
    unsigned short* QKVf = (unsigned short*)(ws + (size_t)(37 << 20));
    unsigned short* Oa   = (unsigned short*)(ws + (size_t)(37 << 20));
    unsigned short* Kb   = (unsigned short*)(ws + (size_t)(69 << 20));
    unsigned short* Vt   = (unsigned short*)(ws + (size_t)(77 << 20));

    cvt_bf16<<<(S * HID) / 1024, 256, 0, stream>>>(hidden, Hb);
    cvt_bf16<<<(QDIM * HID) / 1024, 256, 0, stream>>>(Wq, Wqkv);
    cvt_bf16<<<(KVDIM * HID) / 1024, 256, 0, stream>>>(Wk, Wqkv + (size_t)QDIM * HID);
    cvt_bf16<<<(KVDIM * HID) / 1024, 256, 0, stream>>>(Wv, Wqkv + (size_t)(QDIM + KVDIM) * HID);

    // fused QKV projection: [4096][2304] @ [4096][2304]^T -> [4096][4096]
    // grid = (4096/256)*(4096/256) = 256 tiles, nbn = 16
    bf16_gemm_8ph<unsigned short><<<256, 512, 0, stream>>>(Hb, Wqkv, QKVf, S, QKVDIM, HID, 16);

    rope_kernel<<<(S * 12 * 16) / 256, 256, 0, stream>>>(QKVf, Qb, Kb, pos);
    transpose_v<<<dim3(S / 64, KVDIM / 64), 256, 0, stream>>>(QKVf, Vt);

    attn_kernel<<<512, 256, 0, stream>>>(Qb, Kb, Vt, Oa);

    cvt_bf16<<<(HID * QDIM) / 1024, 256, 0, stream>>>(Wo, Wqkv);
    // O-projection on the same 8-phase kernel: grid = 16 * (2304/256=9) = 144, nbn = 9
    bf16_gemm_8ph<float><<<144, 512, 0, stream>>>(Oa, Wqkv, out, S, HID, QDIM, 9);
}